// Round 8
// baseline (495.803 us; speedup 1.0000x reference)
//
#include <hip/hip_runtime.h>
#include <hip/hip_bf16.h>
#include <hip/hip_fp16.h>
#include <math.h>

#define NN 50000
#define NP 50048            // NN padded to 64-row tiles
#define NE 800000
#define ET (NE + NN)
#define DF 128
#define NH 4
#define HD 512
#define BN_EPS 1e-5f

typedef __hip_bfloat16 bf16;
typedef __attribute__((ext_vector_type(8))) short bf16x8;
typedef __attribute__((ext_vector_type(4))) float f32x4;

// ---------- input conversions ----------
__global__ __launch_bounds__(256) void cvt_x_bf16(const float* __restrict__ in, bf16* __restrict__ out) {
    int i = blockIdx.x * 256 + threadIdx.x;            // 4 elements per thread
    if (i >= NN * DF / 4) return;
    float4 v = reinterpret_cast<const float4*>(in)[i];
    union { bf16 b[4]; short4 s; } u;
    u.b[0] = __float2bfloat16(v.x); u.b[1] = __float2bfloat16(v.y);
    u.b[2] = __float2bfloat16(v.z); u.b[3] = __float2bfloat16(v.w);
    reinterpret_cast<short4*>(out)[i] = u.s;
}

// wsd[layer][o][d] = sum_c W[d, h*128+c] * att[h][c],  o=h (src, 0..3) or 4+h (dst)
__global__ __launch_bounds__(256) void make_wsd(const float* __restrict__ W1, const float* __restrict__ as1,
                                                const float* __restrict__ ad1,
                                                const float* __restrict__ W2, const float* __restrict__ as2,
                                                const float* __restrict__ ad2,
                                                float* __restrict__ wsd) {
    int t = blockIdx.x * 256 + threadIdx.x;   // 0..2047
    if (t >= 2048) return;
    int layer = t >> 10;
    int o = (t >> 7) & 7;
    int d = t & 127;
    int h = o & 3;
    const float* W  = layer ? W2 : W1;
    const float* av = layer ? (o < 4 ? as2 : ad2) : (o < 4 ? as1 : ad1);
    const float* wrow = W + d * HD + h * DF;
    const float* arow = av + h * DF;
    float sum = 0.f;
    for (int c = 0; c < DF; ++c) sum += wrow[c] * arow[c];
    wsd[layer * 1024 + o * DF + d] = sum;
}

// Bt2[layer][c][h*128+d] = 0.25 * W[d][h*128+c]   (stacked, transposed, head-mean folded)
__global__ __launch_bounds__(256) void cvt_bt2(const float* __restrict__ W1, const float* __restrict__ W2,
                                               bf16* __restrict__ B1, bf16* __restrict__ B2) {
    int i = blockIdx.x * 256 + threadIdx.x;   // 0..131071
    if (i >= 2 * DF * HD) return;
    int layer = i >> 16;
    int ii = i & 65535;
    int c = ii >> 9, k = ii & 511;
    int h = k >> 7, d = k & 127;
    const float* W = layer ? W2 : W1;
    bf16* B = layer ? B2 : B1;
    B[ii] = __float2bfloat16(0.25f * W[d * HD + h * DF + c]);
}

// ---------- per-node scores from x: a[n,o] = <x[n], wsd[o]> ----------
__global__ __launch_bounds__(256) void xscore(const bf16* __restrict__ X,
                                              const float* __restrict__ wsd,   // [8][128]
                                              float* __restrict__ a_src,
                                              float* __restrict__ a_dst) {
    __shared__ float w[8][DF];
    reinterpret_cast<float4*>(&w[0][0])[threadIdx.x] = reinterpret_cast<const float4*>(wsd)[threadIdx.x];
    __syncthreads();
    const int n = blockIdx.x * 4 + (threadIdx.x >> 6);
    const int l = threadIdx.x & 63;          // lane owns features 2l, 2l+1
    unsigned xv = reinterpret_cast<const unsigned*>(X)[n * 64 + l];
    float x0 = __uint_as_float(xv << 16);
    float x1 = __uint_as_float(xv & 0xffff0000u);
    float v[8];
    #pragma unroll
    for (int o = 0; o < 8; ++o)
        v[o] = x0 * w[o][2 * l] + x1 * w[o][2 * l + 1];
    #pragma unroll
    for (int off = 1; off < 64; off <<= 1) {
        #pragma unroll
        for (int o = 0; o < 8; ++o) v[o] += __shfl_xor(v[o], off);
    }
    if (l == 0) {
        reinterpret_cast<float4*>(a_src)[n] = make_float4(v[0], v[1], v[2], v[3]);
        reinterpret_cast<float4*>(a_dst)[n] = make_float4(v[4], v[5], v[6], v[7]);
    }
}

// ---------- CSR build (counters padded: one dst per 64B line -> idx<<4) ----------
__global__ __launch_bounds__(256) void count_deg(const int* __restrict__ ei, int* __restrict__ counts) {
    int e = (blockIdx.x * 256 + threadIdx.x) * 2;
    if (e >= ET) return;
    int d0, d1;
    if (e + 1 < NE) {
        int2 dd = *reinterpret_cast<const int2*>(ei + NE + e);
        d0 = dd.x; d1 = dd.y;
    } else {
        d0 = (e < NE) ? ei[NE + e] : (e - NE);
        d1 = (e + 1 < NE) ? ei[NE + e + 1] : (e + 1 - NE);
    }
    atomicAdd(&counts[d0 << 4], 1);
    atomicAdd(&counts[d1 << 4], 1);
}

__global__ __launch_bounds__(256) void scan1(const int* __restrict__ counts, int* __restrict__ bsum) {
    __shared__ int sd[256];
    int i = blockIdx.x * 256 + threadIdx.x;
    sd[threadIdx.x] = (i < NN) ? counts[i << 4] : 0;
    __syncthreads();
    for (int s = 128; s > 0; s >>= 1) {
        if (threadIdx.x < s) sd[threadIdx.x] += sd[threadIdx.x + s];
        __syncthreads();
    }
    if (threadIdx.x == 0) bsum[blockIdx.x] = sd[0];
}

__global__ void scan2(int* __restrict__ bsum, int nb) {
    if (threadIdx.x == 0 && blockIdx.x == 0) {
        int acc = 0;
        for (int i = 0; i < nb; ++i) { int v = bsum[i]; bsum[i] = acc; acc += v; }
    }
}

__global__ __launch_bounds__(256) void scan3(const int* __restrict__ counts, const int* __restrict__ bsum,
                                             int* __restrict__ row_ptr, int* __restrict__ cursor) {
    __shared__ int sd[256];
    int i = blockIdx.x * 256 + threadIdx.x;
    int v = (i < NN) ? counts[i << 4] : 0;
    sd[threadIdx.x] = v;
    __syncthreads();
    for (int s = 1; s < 256; s <<= 1) {
        int t = sd[threadIdx.x];
        int u = (threadIdx.x >= s) ? sd[threadIdx.x - s] : 0;
        __syncthreads();
        sd[threadIdx.x] = t + u;
        __syncthreads();
    }
    int excl = sd[threadIdx.x] - v + bsum[blockIdx.x];
    if (i < NN) { row_ptr[i] = excl; cursor[i << 4] = excl; }
    if (i == 0) row_ptr[NN] = ET;
}

__global__ __launch_bounds__(256) void fill_csr(const int* __restrict__ ei, int* __restrict__ cursor,
                                                int* __restrict__ col) {
    int e = (blockIdx.x * 256 + threadIdx.x) * 2;
    if (e >= ET) return;
    int s0, d0, s1, d1;
    if (e + 1 < NE) {
        int2 ss = *reinterpret_cast<const int2*>(ei + e);
        int2 dd = *reinterpret_cast<const int2*>(ei + NE + e);
        s0 = ss.x; s1 = ss.y; d0 = dd.x; d1 = dd.y;
    } else {
        if (e < NE) { s0 = ei[e]; d0 = ei[NE + e]; } else { s0 = d0 = e - NE; }
        if (e + 1 < NE) { s1 = ei[e + 1]; d1 = ei[NE + e + 1]; } else { s1 = d1 = e + 1 - NE; }
    }
    int p0 = atomicAdd(&cursor[d0 << 4], 1);
    int p1 = atomicAdd(&cursor[d1 << 4], 1);
    col[p0] = s0;
    col[p1] = s1;
}

// ---------- per-edge alpha: one lane per (node, head) ----------
__global__ __launch_bounds__(256) void edge_alpha(const float* __restrict__ a_src,
                                                  const float* __restrict__ a_dst,
                                                  const int* __restrict__ row_ptr,
                                                  const int* __restrict__ col,
                                                  __half* __restrict__ alpha) {
    int t = blockIdx.x * 256 + threadIdx.x;
    int n = t >> 2, h = t & 3;
    if (n >= NN) return;
    const float d = a_dst[n * 4 + h];
    const int start = row_ptr[n], end = row_ptr[n + 1];
    float m = -1e30f, s = 0.f;
    for (int j = start; j < end; ++j) {
        float a = a_src[col[j] * 4 + h] + d;
        a = a > 0.f ? a : 0.2f * a;
        float nm = fmaxf(m, a);
        s = s * __expf(m - nm) + __expf(a - nm);
        m = nm;
    }
    const float inv = 1.0f / s;               // head-mean 0.25 folded into Bt2
    for (int j = start; j < end; ++j) {
        float a = a_src[col[j] * 4 + h] + d;
        a = a > 0.f ? a : 0.2f * a;
        alpha[4 * j + h] = __float2half(__expf(a - m) * inv);
    }
}

// ---------- head-weighted x gather: aggX[n][h*128+d] = sum_e alpha[e,h] x[src,d] ----------
#define EDGE(xu, pu) {                                                               \
    float lo = __uint_as_float((xu) << 16);                                          \
    float hi = __uint_as_float((xu) & 0xffff0000u);                                  \
    float2 f01 = __half22float2(*reinterpret_cast<const __half2*>(&(pu).x));         \
    float2 f23 = __half22float2(*reinterpret_cast<const __half2*>(&(pu).y));         \
    acc[0][0] += f01.x * lo; acc[0][1] += f01.x * hi;                                \
    acc[1][0] += f01.y * lo; acc[1][1] += f01.y * hi;                                \
    acc[2][0] += f23.x * lo; acc[2][1] += f23.x * hi;                                \
    acc[3][0] += f23.y * lo; acc[3][1] += f23.y * hi; }

__global__ __launch_bounds__(256) void aggregate_x(const bf16* __restrict__ X,
                                                   const __half* __restrict__ alpha,
                                                   const int* __restrict__ row_ptr,
                                                   const int* __restrict__ col,
                                                   bf16* __restrict__ aggX) {
    const int n = blockIdx.x * 4 + (threadIdx.x >> 6);
    const int l = threadIdx.x & 63;          // lane owns x features 2l, 2l+1
    const int start = row_ptr[n], end = row_ptr[n + 1];
    const unsigned* __restrict__ X4 = reinterpret_cast<const unsigned*>(X);
    float acc[4][2] = {};
    int j = start;
    for (; j + 4 <= end; j += 4) {
        int c0 = col[j], c1 = col[j + 1], c2 = col[j + 2], c3 = col[j + 3];
        unsigned x0 = X4[c0 * 64 + l];
        unsigned x1 = X4[c1 * 64 + l];
        unsigned x2 = X4[c2 * 64 + l];
        unsigned x3 = X4[c3 * 64 + l];
        uint2 p0 = *reinterpret_cast<const uint2*>(alpha + 4 * j);
        uint2 p1 = *reinterpret_cast<const uint2*>(alpha + 4 * (j + 1));
        uint2 p2 = *reinterpret_cast<const uint2*>(alpha + 4 * (j + 2));
        uint2 p3 = *reinterpret_cast<const uint2*>(alpha + 4 * (j + 3));
        EDGE(x0, p0) EDGE(x1, p1) EDGE(x2, p2) EDGE(x3, p3)
    }
    for (; j < end; ++j) {
        unsigned x0 = X4[col[j] * 64 + l];
        uint2 p0 = *reinterpret_cast<const uint2*>(alpha + 4 * j);
        EDGE(x0, p0)
    }
    unsigned* outp = reinterpret_cast<unsigned*>(aggX) + (size_t)n * 256;
    #pragma unroll
    for (int h = 0; h < 4; ++h) {
        union { bf16 b; unsigned short u; } plo, phi;
        plo.b = __float2bfloat16(acc[h][0]);
        phi.b = __float2bfloat16(acc[h][1]);
        outp[h * 64 + l] = (unsigned)plo.u | ((unsigned)phi.u << 16);
    }
}

// ---------- MFMA GEMM: out[M,128](f32) = A[M,512](bf16) @ Bt[128,512]^T + bias ----------
__global__ __launch_bounds__(256) void gemm_out(const bf16* __restrict__ A,
                                                const bf16* __restrict__ Bt,
                                                const float* __restrict__ bias,
                                                float* __restrict__ out, int M) {
    __shared__ __align__(16) char As[2][16384];   // [64 rows][256B k-chunk], XOR-swizzled
    __shared__ __align__(16) char Bs[2][16384];
    const int tid = threadIdx.x;
    const int m0 = blockIdx.x * 64;
    const int n0 = blockIdx.y * 64;
    const char* Ab = (const char*)A + (size_t)m0 * 1024;     // row stride 512*2 B
    const char* Bb = (const char*)Bt + (size_t)n0 * 1024;
    auto stage = [&](const char* base, char* lds, int kc) {
        #pragma unroll
        for (int i = 0; i < 4; ++i) {
            int d = (tid + i * 256) * 16;
            int row = d >> 8;
            int s = (d & 255) ^ ((row & 7) << 4);
            __builtin_amdgcn_global_load_lds(
                (const __attribute__((address_space(1))) void*)(base + (size_t)row * 1024 + kc * 256 + s),
                (__attribute__((address_space(3))) void*)(lds + d), 16, 0, 0);
        }
    };
    stage(Ab, As[0], 0);
    stage(Bb, Bs[0], 0);
    const int lane = tid & 63;
    const int wave = tid >> 6;
    const int wm = (wave & 1) * 32;
    const int wn = (wave >> 1) * 32;
    const int lr = lane & 15;
    const int lkb = (lane >> 4) * 16;
    f32x4 acc[2][2] = {};
    for (int kc = 0; kc < 4; ++kc) {
        __syncthreads();
        if (kc < 3) {
            stage(Ab, As[(kc + 1) & 1], kc + 1);
            stage(Bb, Bs[(kc + 1) & 1], kc + 1);
        }
        const char* Ac = As[kc & 1];
        const char* Bc = Bs[kc & 1];
        #pragma unroll
        for (int kk = 0; kk < 4; ++kk) {
            int kb = kk * 64 + lkb;
            int ra0 = wm + lr, ra1 = wm + 16 + lr;
            int rb0 = wn + lr, rb1 = wn + 16 + lr;
            bf16x8 a0 = *(const bf16x8*)(Ac + ((ra0 * 256 + kb) ^ ((ra0 & 7) << 4)));
            bf16x8 a1 = *(const bf16x8*)(Ac + ((ra1 * 256 + kb) ^ ((ra1 & 7) << 4)));
            bf16x8 b0 = *(const bf16x8*)(Bc + ((rb0 * 256 + kb) ^ ((rb0 & 7) << 4)));
            bf16x8 b1 = *(const bf16x8*)(Bc + ((rb1 * 256 + kb) ^ ((rb1 & 7) << 4)));
            acc[0][0] = __builtin_amdgcn_mfma_f32_16x16x32_bf16(a0, b0, acc[0][0], 0, 0, 0);
            acc[0][1] = __builtin_amdgcn_mfma_f32_16x16x32_bf16(a0, b1, acc[0][1], 0, 0, 0);
            acc[1][0] = __builtin_amdgcn_mfma_f32_16x16x32_bf16(a1, b0, acc[1][0], 0, 0, 0);
            acc[1][1] = __builtin_amdgcn_mfma_f32_16x16x32_bf16(a1, b1, acc[1][1], 0, 0, 0);
        }
    }
    const int orow = (lane >> 4) * 4;
    float bcol[2];
    bcol[0] = bias[n0 + wn + lr];
    bcol[1] = bias[n0 + wn + 16 + lr];
    #pragma unroll
    for (int mi = 0; mi < 2; ++mi) {
        #pragma unroll
        for (int r = 0; r < 4; ++r) {
            int gr = m0 + wm + mi * 16 + orow + r;
            if (gr < M) {
                #pragma unroll
                for (int ni = 0; ni < 2; ++ni)
                    out[(size_t)gr * DF + n0 + wn + ni * 16 + lr] = acc[mi][ni][r] + bcol[ni];
            }
        }
    }
}

// ---------- BatchNorm ----------
__global__ __launch_bounds__(256) void bn_stats(const float* __restrict__ x, float* __restrict__ stats) {
    const int c = threadIdx.x & 127;
    const int half = threadIdx.x >> 7;
    float sum = 0.f, sq = 0.f;
    for (int r = blockIdx.x * 2 + half; r < NN; r += gridDim.x * 2) {
        float v = x[r * DF + c];
        sum += v; sq += v * v;
    }
    __shared__ float s1[256], s2[256];
    s1[threadIdx.x] = sum; s2[threadIdx.x] = sq;
    __syncthreads();
    if (threadIdx.x < 128) {
        atomicAdd(&stats[c], s1[threadIdx.x] + s1[threadIdx.x + 128]);
        atomicAdd(&stats[128 + c], s2[threadIdx.x] + s2[threadIdx.x + 128]);
    }
}

__global__ __launch_bounds__(256) void bn_apply_bf16(const float* __restrict__ x, const float* __restrict__ stats,
                                                     const float* __restrict__ gamma, const float* __restrict__ beta,
                                                     bf16* __restrict__ out) {
    int i = blockIdx.x * blockDim.x + threadIdx.x;
    if (i >= NN * DF) return;
    int c = i & 127;
    float mu = stats[c] * (1.f / NN);
    float var = stats[128 + c] * (1.f / NN) - mu * mu;
    float v = (x[i] - mu) * rsqrtf(var + BN_EPS) * gamma[c] + beta[c];
    out[i] = __float2bfloat16(fmaxf(v, 0.f));
}

__global__ __launch_bounds__(256) void bn_apply(const float* __restrict__ x, const float* __restrict__ stats,
                                                const float* __restrict__ gamma, const float* __restrict__ beta,
                                                float* __restrict__ out) {
    int i = blockIdx.x * blockDim.x + threadIdx.x;
    if (i >= NN * DF) return;
    int c = i & 127;
    float mu = stats[c] * (1.f / NN);
    float var = stats[128 + c] * (1.f / NN) - mu * mu;
    float v = (x[i] - mu) * rsqrtf(var + BN_EPS) * gamma[c] + beta[c];
    out[i] = fmaxf(v, 0.f);
}

extern "C" void kernel_launch(void* const* d_in, const int* in_sizes, int n_in,
                              void* d_out, int out_size, void* d_ws, size_t ws_size,
                              hipStream_t stream) {
    (void)in_sizes; (void)n_in; (void)out_size; (void)ws_size;
    const float* x   = (const float*)d_in[0];
    const int*   ei  = (const int*)d_in[1];
    const float* W1  = (const float*)d_in[2];
    const float* as1 = (const float*)d_in[3];
    const float* ad1 = (const float*)d_in[4];
    const float* b1  = (const float*)d_in[5];
    const float* g1  = (const float*)d_in[6];
    const float* be1 = (const float*)d_in[7];
    const float* W2  = (const float*)d_in[8];
    const float* as2 = (const float*)d_in[9];
    const float* ad2 = (const float*)d_in[10];
    const float* b2  = (const float*)d_in[11];
    const float* g2  = (const float*)d_in[12];
    const float* be2 = (const float*)d_in[13];
    float* out = (float*)d_out;

    char* ws = (char*)d_ws;
    size_t off = 0;
    auto alloc = [&](size_t bytes) -> void* {
        void* p = ws + off;
        off += (bytes + 255) & ~(size_t)255;
        return p;
    };
    bf16*   aggX    = (bf16*)alloc((size_t)NP * HD * 2);      // 51.25 MB
    bf16*   xb      = (bf16*)alloc((size_t)NP * DF * 2);      // 12.8 MB (padded)
    bf16*   Bt2a    = (bf16*)alloc((size_t)DF * HD * 2);      // 128 KB
    bf16*   Bt2b    = (bf16*)alloc((size_t)DF * HD * 2);
    float*  wsd     = (float*)alloc(2 * 1024 * 4);            // 8 KB
    float*  a_src   = (float*)alloc((size_t)NN * NH * 4);
    float*  a_dst   = (float*)alloc((size_t)NN * NH * 4);
    int*    row_ptr = (int*)alloc((size_t)(NN + 1) * 4);
    int*    bsum    = (int*)alloc(256 * 4);
    int*    colidx  = (int*)alloc((size_t)ET * 4);
    __half* alpha   = (__half*)alloc((size_t)ET * 8);         // 6.8 MB
    float*  agg     = (float*)alloc((size_t)NN * DF * 4);     // 25.6 MB
    float*  stats   = (float*)alloc(256 * 4);
    // counts/cursor: padded 64B-per-dst counters (3.2 MB each), aliased into agg
    // (agg is first written by gemm_out, long after fill_csr completes)
    int*    counts  = (int*)agg;
    int*    cursor  = (int*)((char*)agg + ((size_t)NP << 6));
    // high-water ~101.9 MB (<= R1-proven 107.4 MB)

    const int NB = (NN + 255) / 256;        // 196
    const int EB2 = (ET / 2 + 255) / 256;   // 1661
    dim3 ogrid(NP / 64, 2);                 // 782 x 2

    // ---- prep + CSR build ----
    cvt_x_bf16<<<(NN * DF / 4 + 255) / 256, 256, 0, stream>>>(x, xb);
    make_wsd<<<8, 256, 0, stream>>>(W1, as1, ad1, W2, as2, ad2, wsd);
    cvt_bt2<<<(2 * DF * HD + 255) / 256, 256, 0, stream>>>(W1, W2, Bt2a, Bt2b);
    hipMemsetAsync(counts, 0, (size_t)NP << 6, stream);
    count_deg<<<EB2, 256, 0, stream>>>(ei, counts);
    scan1<<<NB, 256, 0, stream>>>(counts, bsum);
    scan2<<<1, 64, 0, stream>>>(bsum, NB);
    scan3<<<NB, 256, 0, stream>>>(counts, bsum, row_ptr, cursor);
    fill_csr<<<EB2, 256, 0, stream>>>(ei, cursor, colidx);

    // ---- layer 1 ----
    xscore<<<NN / 4, 256, 0, stream>>>(xb, wsd, a_src, a_dst);
    edge_alpha<<<(NN * 4 + 255) / 256, 256, 0, stream>>>(a_src, a_dst, row_ptr, colidx, alpha);
    aggregate_x<<<NN / 4, 256, 0, stream>>>(xb, alpha, row_ptr, colidx, aggX);
    gemm_out<<<ogrid, 256, 0, stream>>>(aggX, Bt2a, b1, agg, NN);
    hipMemsetAsync(stats, 0, 256 * 4, stream);
    bn_stats<<<200, 256, 0, stream>>>(agg, stats);
    bn_apply_bf16<<<(NN * DF + 255) / 256, 256, 0, stream>>>(agg, stats, g1, be1, xb);

    // ---- layer 2 ----
    xscore<<<NN / 4, 256, 0, stream>>>(xb, wsd + 1024, a_src, a_dst);
    edge_alpha<<<(NN * 4 + 255) / 256, 256, 0, stream>>>(a_src, a_dst, row_ptr, colidx, alpha);
    aggregate_x<<<NN / 4, 256, 0, stream>>>(xb, alpha, row_ptr, colidx, aggX);
    gemm_out<<<ogrid, 256, 0, stream>>>(aggX, Bt2b, b2, agg, NN);
    hipMemsetAsync(stats, 0, 256 * 4, stream);
    bn_stats<<<200, 256, 0, stream>>>(agg, stats);
    bn_apply<<<(NN * DF + 255) / 256, 256, 0, stream>>>(agg, stats, g2, be2, out);
}

// Round 9
// 456.076 us; speedup vs baseline: 1.0871x; 1.0871x over previous
//
#include <hip/hip_runtime.h>
#include <hip/hip_bf16.h>
#include <hip/hip_fp16.h>
#include <math.h>

#define NN 50000
#define NP 50048            // NN padded to 64-row tiles
#define NE 800000
#define ET (NE + NN)
#define DF 128
#define NH 4
#define HD 512
#define BN_EPS 1e-5f

typedef __hip_bfloat16 bf16;
typedef __attribute__((ext_vector_type(8))) short bf16x8;
typedef __attribute__((ext_vector_type(4))) float f32x4;

struct alignas(8) h2x2 { __half2 a, b; };

// ---------- input conversions ----------
__global__ __launch_bounds__(256) void cvt_x_bf16(const float* __restrict__ in, bf16* __restrict__ out) {
    int i = blockIdx.x * 256 + threadIdx.x;            // 4 elements per thread
    if (i >= NN * DF / 4) return;
    float4 v = reinterpret_cast<const float4*>(in)[i];
    union { bf16 b[4]; short4 s; } u;
    u.b[0] = __float2bfloat16(v.x); u.b[1] = __float2bfloat16(v.y);
    u.b[2] = __float2bfloat16(v.z); u.b[3] = __float2bfloat16(v.w);
    reinterpret_cast<short4*>(out)[i] = u.s;
}

// wsd[layer][o][d] = sum_c W[d, h*128+c] * att[h][c],  o=h (src, 0..3) or 4+h (dst)
__global__ __launch_bounds__(256) void make_wsd(const float* __restrict__ W1, const float* __restrict__ as1,
                                                const float* __restrict__ ad1,
                                                const float* __restrict__ W2, const float* __restrict__ as2,
                                                const float* __restrict__ ad2,
                                                float* __restrict__ wsd) {
    int t = blockIdx.x * 256 + threadIdx.x;   // 0..2047
    if (t >= 2048) return;
    int layer = t >> 10;
    int o = (t >> 7) & 7;
    int d = t & 127;
    int h = o & 3;
    const float* W  = layer ? W2 : W1;
    const float* av = layer ? (o < 4 ? as2 : ad2) : (o < 4 ? as1 : ad1);
    const float* wrow = W + d * HD + h * DF;
    const float* arow = av + h * DF;
    float sum = 0.f;
    for (int c = 0; c < DF; ++c) sum += wrow[c] * arow[c];
    wsd[layer * 1024 + o * DF + d] = sum;
}

// Bt2[layer][c][h*128+d] = 0.25 * W[d][h*128+c]   (stacked, transposed, head-mean folded)
__global__ __launch_bounds__(256) void cvt_bt2(const float* __restrict__ W1, const float* __restrict__ W2,
                                               bf16* __restrict__ B1, bf16* __restrict__ B2) {
    int i = blockIdx.x * 256 + threadIdx.x;   // 0..131071
    if (i >= 2 * DF * HD) return;
    int layer = i >> 16;
    int ii = i & 65535;
    int c = ii >> 9, k = ii & 511;
    int h = k >> 7, d = k & 127;
    const float* W = layer ? W2 : W1;
    bf16* B = layer ? B2 : B1;
    B[ii] = __float2bfloat16(0.25f * W[d * HD + h * DF + c]);
}

// ---------- per-node scores from x: a[n,o] = <x[n], wsd[o]> ----------
__global__ __launch_bounds__(256) void xscore(const bf16* __restrict__ X,
                                              const float* __restrict__ wsd,   // [8][128]
                                              float* __restrict__ a_src,
                                              float* __restrict__ a_dst) {
    __shared__ float w[8][DF];
    reinterpret_cast<float4*>(&w[0][0])[threadIdx.x] = reinterpret_cast<const float4*>(wsd)[threadIdx.x];
    __syncthreads();
    const int n = blockIdx.x * 4 + (threadIdx.x >> 6);
    const int l = threadIdx.x & 63;          // lane owns features 2l, 2l+1
    unsigned xv = reinterpret_cast<const unsigned*>(X)[n * 64 + l];
    float x0 = __uint_as_float(xv << 16);
    float x1 = __uint_as_float(xv & 0xffff0000u);
    float v[8];
    #pragma unroll
    for (int o = 0; o < 8; ++o)
        v[o] = x0 * w[o][2 * l] + x1 * w[o][2 * l + 1];
    #pragma unroll
    for (int off = 1; off < 64; off <<= 1) {
        #pragma unroll
        for (int o = 0; o < 8; ++o) v[o] += __shfl_xor(v[o], off);
    }
    if (l == 0) {
        reinterpret_cast<float4*>(a_src)[n] = make_float4(v[0], v[1], v[2], v[3]);
        reinterpret_cast<float4*>(a_dst)[n] = make_float4(v[4], v[5], v[6], v[7]);
    }
}

// ---------- CSR build: single atomic pass (rank trick) ----------
// rank[e] = position of edge e within its dst's segment (atomic return value)
__global__ __launch_bounds__(256) void count_rank(const int* __restrict__ ei, int* __restrict__ counts,
                                                  int* __restrict__ rank) {
    int e = (blockIdx.x * 256 + threadIdx.x) * 2;
    if (e >= ET) return;
    int d0, d1;
    if (e + 1 < NE) {
        int2 dd = *reinterpret_cast<const int2*>(ei + NE + e);
        d0 = dd.x; d1 = dd.y;
    } else {
        d0 = (e < NE) ? ei[NE + e] : (e - NE);
        d1 = (e + 1 < NE) ? ei[NE + e + 1] : (e + 1 - NE);
    }
    rank[e]     = atomicAdd(&counts[d0 << 4], 1);
    rank[e + 1] = atomicAdd(&counts[d1 << 4], 1);
}

__global__ __launch_bounds__(256) void scan1(const int* __restrict__ counts, int* __restrict__ bsum) {
    __shared__ int sd[256];
    int i = blockIdx.x * 256 + threadIdx.x;
    sd[threadIdx.x] = (i < NN) ? counts[i << 4] : 0;
    __syncthreads();
    for (int s = 128; s > 0; s >>= 1) {
        if (threadIdx.x < s) sd[threadIdx.x] += sd[threadIdx.x + s];
        __syncthreads();
    }
    if (threadIdx.x == 0) bsum[blockIdx.x] = sd[0];
}

__global__ void scan2(int* __restrict__ bsum, int nb) {
    if (threadIdx.x == 0 && blockIdx.x == 0) {
        int acc = 0;
        for (int i = 0; i < nb; ++i) { int v = bsum[i]; bsum[i] = acc; acc += v; }
    }
}

__global__ __launch_bounds__(256) void scan3(const int* __restrict__ counts, const int* __restrict__ bsum,
                                             int* __restrict__ row_ptr) {
    __shared__ int sd[256];
    int i = blockIdx.x * 256 + threadIdx.x;
    int v = (i < NN) ? counts[i << 4] : 0;
    sd[threadIdx.x] = v;
    __syncthreads();
    for (int s = 1; s < 256; s <<= 1) {
        int t = sd[threadIdx.x];
        int u = (threadIdx.x >= s) ? sd[threadIdx.x - s] : 0;
        __syncthreads();
        sd[threadIdx.x] = t + u;
        __syncthreads();
    }
    int excl = sd[threadIdx.x] - v + bsum[blockIdx.x];
    if (i < NN) row_ptr[i] = excl;
    if (i == 0) row_ptr[NN] = ET;
}

// non-atomic scatter: col[row_ptr[d] + rank[e]] = src(e)
__global__ __launch_bounds__(256) void fill_scatter(const int* __restrict__ ei, const int* __restrict__ rank,
                                                    const int* __restrict__ row_ptr, int* __restrict__ col) {
    int e = (blockIdx.x * 256 + threadIdx.x) * 2;
    if (e >= ET) return;
    int s0, d0, s1, d1;
    if (e + 1 < NE) {
        int2 ss = *reinterpret_cast<const int2*>(ei + e);
        int2 dd = *reinterpret_cast<const int2*>(ei + NE + e);
        s0 = ss.x; s1 = ss.y; d0 = dd.x; d1 = dd.y;
    } else {
        if (e < NE) { s0 = ei[e]; d0 = ei[NE + e]; } else { s0 = d0 = e - NE; }
        if (e + 1 < NE) { s1 = ei[e + 1]; d1 = ei[NE + e + 1]; } else { s1 = d1 = e + 1 - NE; }
    }
    int2 rk = *reinterpret_cast<const int2*>(rank + e);
    col[row_ptr[d0] + rk.x] = s0;
    col[row_ptr[d1] + rk.y] = s1;
}

// ---------- per-edge alpha: one WAVE per node, single gather pass ----------
__global__ __launch_bounds__(256) void edge_alpha(const float* __restrict__ a_src,
                                                  const float* __restrict__ a_dst,
                                                  const int* __restrict__ row_ptr,
                                                  const int* __restrict__ col,
                                                  __half* __restrict__ alpha) {
    const int n = blockIdx.x * 4 + (threadIdx.x >> 6);
    const int l = threadIdx.x & 63;
    const int start = row_ptr[n], end = row_ptr[n + 1];
    const float4 ad4 = reinterpret_cast<const float4*>(a_dst)[n];
    const float4* __restrict__ as4 = reinterpret_cast<const float4*>(a_src);
    if (end - start <= 64) {                       // common case: deg <= 64
        const int j = start + l;
        float lv[4] = {-1e30f, -1e30f, -1e30f, -1e30f};
        if (j < end) {
            float4 a = as4[col[j]];
            lv[0] = a.x + ad4.x; lv[1] = a.y + ad4.y; lv[2] = a.z + ad4.z; lv[3] = a.w + ad4.w;
            #pragma unroll
            for (int h = 0; h < 4; ++h) lv[h] = lv[h] > 0.f ? lv[h] : 0.2f * lv[h];
        }
        float m[4], p[4], s[4];
        #pragma unroll
        for (int h = 0; h < 4; ++h) m[h] = lv[h];
        #pragma unroll
        for (int off = 1; off < 64; off <<= 1) {
            #pragma unroll
            for (int h = 0; h < 4; ++h) m[h] = fmaxf(m[h], __shfl_xor(m[h], off));
        }
        #pragma unroll
        for (int h = 0; h < 4; ++h) { p[h] = (j < end) ? __expf(lv[h] - m[h]) : 0.f; s[h] = p[h]; }
        #pragma unroll
        for (int off = 1; off < 64; off <<= 1) {
            #pragma unroll
            for (int h = 0; h < 4; ++h) s[h] += __shfl_xor(s[h], off);
        }
        if (j < end) {
            h2x2 o;
            o.a = __floats2half2_rn(p[0] / s[0], p[1] / s[1]);
            o.b = __floats2half2_rn(p[2] / s[2], p[3] / s[3]);
            reinterpret_cast<h2x2*>(alpha)[j] = o;
        }
    } else {                                       // rare: deg > 64, chunked online
        float m[4] = {-1e30f, -1e30f, -1e30f, -1e30f}, s[4] = {0.f, 0.f, 0.f, 0.f};
        for (int base = start; base < end; base += 64) {
            const int j = base + l;
            float lv[4] = {-1e30f, -1e30f, -1e30f, -1e30f};
            if (j < end) {
                float4 a = as4[col[j]];
                lv[0] = a.x + ad4.x; lv[1] = a.y + ad4.y; lv[2] = a.z + ad4.z; lv[3] = a.w + ad4.w;
                #pragma unroll
                for (int h = 0; h < 4; ++h) lv[h] = lv[h] > 0.f ? lv[h] : 0.2f * lv[h];
            }
            float cm[4], cp[4];
            #pragma unroll
            for (int h = 0; h < 4; ++h) cm[h] = lv[h];
            #pragma unroll
            for (int off = 1; off < 64; off <<= 1) {
                #pragma unroll
                for (int h = 0; h < 4; ++h) cm[h] = fmaxf(cm[h], __shfl_xor(cm[h], off));
            }
            #pragma unroll
            for (int h = 0; h < 4; ++h) {
                float nm = fmaxf(m[h], cm[h]);
                cp[h] = (j < end) ? __expf(lv[h] - nm) : 0.f;
                s[h] *= __expf(m[h] - nm);
                m[h] = nm;
            }
            #pragma unroll
            for (int off = 1; off < 64; off <<= 1) {
                #pragma unroll
                for (int h = 0; h < 4; ++h) cp[h] += __shfl_xor(cp[h], off);
            }
            #pragma unroll
            for (int h = 0; h < 4; ++h) s[h] += cp[h];
        }
        for (int base = start; base < end; base += 64) {
            const int j = base + l;
            if (j < end) {
                float4 a = as4[col[j]];
                float v0 = a.x + ad4.x, v1 = a.y + ad4.y, v2 = a.z + ad4.z, v3 = a.w + ad4.w;
                v0 = v0 > 0.f ? v0 : 0.2f * v0; v1 = v1 > 0.f ? v1 : 0.2f * v1;
                v2 = v2 > 0.f ? v2 : 0.2f * v2; v3 = v3 > 0.f ? v3 : 0.2f * v3;
                h2x2 o;
                o.a = __floats2half2_rn(__expf(v0 - m[0]) / s[0], __expf(v1 - m[1]) / s[1]);
                o.b = __floats2half2_rn(__expf(v2 - m[2]) / s[2], __expf(v3 - m[3]) / s[3]);
                reinterpret_cast<h2x2*>(alpha)[j] = o;
            }
        }
    }
}

// ---------- head-weighted x gather: aggX[n][h*128+d] = sum_e alpha[e,h] x[src,d] ----------
#define EDGE(xu, pu) {                                                               \
    float lo = __uint_as_float((xu) << 16);                                          \
    float hi = __uint_as_float((xu) & 0xffff0000u);                                  \
    float2 f01 = __half22float2(*reinterpret_cast<const __half2*>(&(pu).x));         \
    float2 f23 = __half22float2(*reinterpret_cast<const __half2*>(&(pu).y));         \
    acc[0][0] += f01.x * lo; acc[0][1] += f01.x * hi;                                \
    acc[1][0] += f01.y * lo; acc[1][1] += f01.y * hi;                                \
    acc[2][0] += f23.x * lo; acc[2][1] += f23.x * hi;                                \
    acc[3][0] += f23.y * lo; acc[3][1] += f23.y * hi; }

__global__ __launch_bounds__(256) void aggregate_x(const bf16* __restrict__ X,
                                                   const __half* __restrict__ alpha,
                                                   const int* __restrict__ row_ptr,
                                                   const int* __restrict__ col,
                                                   bf16* __restrict__ aggX) {
    const int n = blockIdx.x * 4 + (threadIdx.x >> 6);
    const int l = threadIdx.x & 63;          // lane owns x features 2l, 2l+1
    const int start = row_ptr[n], end = row_ptr[n + 1];
    const unsigned* __restrict__ X4 = reinterpret_cast<const unsigned*>(X);
    float acc[4][2] = {};
    int j = start;
    for (; j + 4 <= end; j += 4) {
        int c0 = col[j], c1 = col[j + 1], c2 = col[j + 2], c3 = col[j + 3];
        unsigned x0 = X4[c0 * 64 + l];
        unsigned x1 = X4[c1 * 64 + l];
        unsigned x2 = X4[c2 * 64 + l];
        unsigned x3 = X4[c3 * 64 + l];
        uint2 p0 = *reinterpret_cast<const uint2*>(alpha + 4 * j);
        uint2 p1 = *reinterpret_cast<const uint2*>(alpha + 4 * (j + 1));
        uint2 p2 = *reinterpret_cast<const uint2*>(alpha + 4 * (j + 2));
        uint2 p3 = *reinterpret_cast<const uint2*>(alpha + 4 * (j + 3));
        EDGE(x0, p0) EDGE(x1, p1) EDGE(x2, p2) EDGE(x3, p3)
    }
    for (; j < end; ++j) {
        unsigned x0 = X4[col[j] * 64 + l];
        uint2 p0 = *reinterpret_cast<const uint2*>(alpha + 4 * j);
        EDGE(x0, p0)
    }
    unsigned* outp = reinterpret_cast<unsigned*>(aggX) + (size_t)n * 256;
    #pragma unroll
    for (int h = 0; h < 4; ++h) {
        union { bf16 b; unsigned short u; } plo, phi;
        plo.b = __float2bfloat16(acc[h][0]);
        phi.b = __float2bfloat16(acc[h][1]);
        outp[h * 64 + l] = (unsigned)plo.u | ((unsigned)phi.u << 16);
    }
}

// ---------- MFMA GEMM: out[M,128](f32) = A[M,512](bf16) @ Bt[128,512]^T + bias ----------
__global__ __launch_bounds__(256) void gemm_out(const bf16* __restrict__ A,
                                                const bf16* __restrict__ Bt,
                                                const float* __restrict__ bias,
                                                float* __restrict__ out, int M) {
    __shared__ __align__(16) char As[2][16384];   // [64 rows][256B k-chunk], XOR-swizzled
    __shared__ __align__(16) char Bs[2][16384];
    const int tid = threadIdx.x;
    const int m0 = blockIdx.x * 64;
    const int n0 = blockIdx.y * 64;
    const char* Ab = (const char*)A + (size_t)m0 * 1024;     // row stride 512*2 B
    const char* Bb = (const char*)Bt + (size_t)n0 * 1024;
    auto stage = [&](const char* base, char* lds, int kc) {
        #pragma unroll
        for (int i = 0; i < 4; ++i) {
            int d = (tid + i * 256) * 16;
            int row = d >> 8;
            int s = (d & 255) ^ ((row & 7) << 4);
            __builtin_amdgcn_global_load_lds(
                (const __attribute__((address_space(1))) void*)(base + (size_t)row * 1024 + kc * 256 + s),
                (__attribute__((address_space(3))) void*)(lds + d), 16, 0, 0);
        }
    };
    stage(Ab, As[0], 0);
    stage(Bb, Bs[0], 0);
    const int lane = tid & 63;
    const int wave = tid >> 6;
    const int wm = (wave & 1) * 32;
    const int wn = (wave >> 1) * 32;
    const int lr = lane & 15;
    const int lkb = (lane >> 4) * 16;
    f32x4 acc[2][2] = {};
    for (int kc = 0; kc < 4; ++kc) {
        __syncthreads();
        if (kc < 3) {
            stage(Ab, As[(kc + 1) & 1], kc + 1);
            stage(Bb, Bs[(kc + 1) & 1], kc + 1);
        }
        const char* Ac = As[kc & 1];
        const char* Bc = Bs[kc & 1];
        #pragma unroll
        for (int kk = 0; kk < 4; ++kk) {
            int kb = kk * 64 + lkb;
            int ra0 = wm + lr, ra1 = wm + 16 + lr;
            int rb0 = wn + lr, rb1 = wn + 16 + lr;
            bf16x8 a0 = *(const bf16x8*)(Ac + ((ra0 * 256 + kb) ^ ((ra0 & 7) << 4)));
            bf16x8 a1 = *(const bf16x8*)(Ac + ((ra1 * 256 + kb) ^ ((ra1 & 7) << 4)));
            bf16x8 b0 = *(const bf16x8*)(Bc + ((rb0 * 256 + kb) ^ ((rb0 & 7) << 4)));
            bf16x8 b1 = *(const bf16x8*)(Bc + ((rb1 * 256 + kb) ^ ((rb1 & 7) << 4)));
            acc[0][0] = __builtin_amdgcn_mfma_f32_16x16x32_bf16(a0, b0, acc[0][0], 0, 0, 0);
            acc[0][1] = __builtin_amdgcn_mfma_f32_16x16x32_bf16(a0, b1, acc[0][1], 0, 0, 0);
            acc[1][0] = __builtin_amdgcn_mfma_f32_16x16x32_bf16(a1, b0, acc[1][0], 0, 0, 0);
            acc[1][1] = __builtin_amdgcn_mfma_f32_16x16x32_bf16(a1, b1, acc[1][1], 0, 0, 0);
        }
    }
    const int orow = (lane >> 4) * 4;
    float bcol[2];
    bcol[0] = bias[n0 + wn + lr];
    bcol[1] = bias[n0 + wn + 16 + lr];
    #pragma unroll
    for (int mi = 0; mi < 2; ++mi) {
        #pragma unroll
        for (int r = 0; r < 4; ++r) {
            int gr = m0 + wm + mi * 16 + orow + r;
            if (gr < M) {
                #pragma unroll
                for (int ni = 0; ni < 2; ++ni)
                    out[(size_t)gr * DF + n0 + wn + ni * 16 + lr] = acc[mi][ni][r] + bcol[ni];
            }
        }
    }
}

// ---------- BatchNorm ----------
__global__ __launch_bounds__(256) void bn_stats(const float* __restrict__ x, float* __restrict__ stats) {
    const int c = threadIdx.x & 127;
    const int half = threadIdx.x >> 7;
    float sum = 0.f, sq = 0.f;
    for (int r = blockIdx.x * 2 + half; r < NN; r += gridDim.x * 2) {
        float v = x[r * DF + c];
        sum += v; sq += v * v;
    }
    __shared__ float s1[256], s2[256];
    s1[threadIdx.x] = sum; s2[threadIdx.x] = sq;
    __syncthreads();
    if (threadIdx.x < 128) {
        atomicAdd(&stats[c], s1[threadIdx.x] + s1[threadIdx.x + 128]);
        atomicAdd(&stats[128 + c], s2[threadIdx.x] + s2[threadIdx.x + 128]);
    }
}

__global__ __launch_bounds__(256) void bn_apply_bf16(const float* __restrict__ x, const float* __restrict__ stats,
                                                     const float* __restrict__ gamma, const float* __restrict__ beta,
                                                     bf16* __restrict__ out) {
    int i = blockIdx.x * blockDim.x + threadIdx.x;
    if (i >= NN * DF) return;
    int c = i & 127;
    float mu = stats[c] * (1.f / NN);
    float var = stats[128 + c] * (1.f / NN) - mu * mu;
    float v = (x[i] - mu) * rsqrtf(var + BN_EPS) * gamma[c] + beta[c];
    out[i] = __float2bfloat16(fmaxf(v, 0.f));
}

__global__ __launch_bounds__(256) void bn_apply(const float* __restrict__ x, const float* __restrict__ stats,
                                                const float* __restrict__ gamma, const float* __restrict__ beta,
                                                float* __restrict__ out) {
    int i = blockIdx.x * blockDim.x + threadIdx.x;
    if (i >= NN * DF) return;
    int c = i & 127;
    float mu = stats[c] * (1.f / NN);
    float var = stats[128 + c] * (1.f / NN) - mu * mu;
    float v = (x[i] - mu) * rsqrtf(var + BN_EPS) * gamma[c] + beta[c];
    out[i] = fmaxf(v, 0.f);
}

extern "C" void kernel_launch(void* const* d_in, const int* in_sizes, int n_in,
                              void* d_out, int out_size, void* d_ws, size_t ws_size,
                              hipStream_t stream) {
    (void)in_sizes; (void)n_in; (void)out_size; (void)ws_size;
    const float* x   = (const float*)d_in[0];
    const int*   ei  = (const int*)d_in[1];
    const float* W1  = (const float*)d_in[2];
    const float* as1 = (const float*)d_in[3];
    const float* ad1 = (const float*)d_in[4];
    const float* b1  = (const float*)d_in[5];
    const float* g1  = (const float*)d_in[6];
    const float* be1 = (const float*)d_in[7];
    const float* W2  = (const float*)d_in[8];
    const float* as2 = (const float*)d_in[9];
    const float* ad2 = (const float*)d_in[10];
    const float* b2  = (const float*)d_in[11];
    const float* g2  = (const float*)d_in[12];
    const float* be2 = (const float*)d_in[13];
    float* out = (float*)d_out;

    char* ws = (char*)d_ws;
    size_t off = 0;
    auto alloc = [&](size_t bytes) -> void* {
        void* p = ws + off;
        off += (bytes + 255) & ~(size_t)255;
        return p;
    };
    bf16*   aggX    = (bf16*)alloc((size_t)NP * HD * 2);      // 51.25 MB
    bf16*   xb      = (bf16*)alloc((size_t)NP * DF * 2);      // 12.8 MB (padded)
    bf16*   Bt2a    = (bf16*)alloc((size_t)DF * HD * 2);      // 128 KB
    bf16*   Bt2b    = (bf16*)alloc((size_t)DF * HD * 2);
    float*  wsd     = (float*)alloc(2 * 1024 * 4);            // 8 KB
    float*  a_src   = (float*)alloc((size_t)NN * NH * 4);
    float*  a_dst   = (float*)alloc((size_t)NN * NH * 4);
    int*    row_ptr = (int*)alloc((size_t)(NN + 1) * 4);
    int*    bsum    = (int*)alloc(256 * 4);
    int*    colidx  = (int*)alloc((size_t)ET * 4);
    __half* alpha   = (__half*)alloc((size_t)ET * 8);         // 6.8 MB
    float*  agg     = (float*)alloc((size_t)NN * DF * 4);     // 25.6 MB
    float*  stats   = (float*)alloc(256 * 4);
    // counts (padded 64B/dst, 3.2MB) + rank (3.4MB) aliased into agg
    // (agg is first written by gemm_out, long after CSR build completes)
    int*    counts  = (int*)agg;
    int*    rank    = (int*)((char*)agg + ((size_t)NP << 6));
    // high-water ~101.9 MB (<= R1-proven 107.4 MB)

    const int NB = (NN + 255) / 256;        // 196
    const int EB2 = (ET / 2 + 255) / 256;   // 1661
    dim3 ogrid(NP / 64, 2);                 // 782 x 2

    // ---- prep + CSR build (single atomic pass) ----
    cvt_x_bf16<<<(NN * DF / 4 + 255) / 256, 256, 0, stream>>>(x, xb);
    make_wsd<<<8, 256, 0, stream>>>(W1, as1, ad1, W2, as2, ad2, wsd);
    cvt_bt2<<<(2 * DF * HD + 255) / 256, 256, 0, stream>>>(W1, W2, Bt2a, Bt2b);
    hipMemsetAsync(counts, 0, (size_t)NP << 6, stream);
    count_rank<<<EB2, 256, 0, stream>>>(ei, counts, rank);
    scan1<<<NB, 256, 0, stream>>>(counts, bsum);
    scan2<<<1, 64, 0, stream>>>(bsum, NB);
    scan3<<<NB, 256, 0, stream>>>(counts, bsum, row_ptr);
    fill_scatter<<<EB2, 256, 0, stream>>>(ei, rank, row_ptr, colidx);

    // ---- layer 1 ----
    xscore<<<NN / 4, 256, 0, stream>>>(xb, wsd, a_src, a_dst);
    edge_alpha<<<NN / 4, 256, 0, stream>>>(a_src, a_dst, row_ptr, colidx, alpha);
    aggregate_x<<<NN / 4, 256, 0, stream>>>(xb, alpha, row_ptr, colidx, aggX);
    gemm_out<<<ogrid, 256, 0, stream>>>(aggX, Bt2a, b1, agg, NN);
    hipMemsetAsync(stats, 0, 256 * 4, stream);
    bn_stats<<<200, 256, 0, stream>>>(agg, stats);
    bn_apply_bf16<<<(NN * DF + 255) / 256, 256, 0, stream>>>(agg, stats, g1, be1, xb);

    // ---- layer 2 ----
    xscore<<<NN / 4, 256, 0, stream>>>(xb, wsd + 1024, a_src, a_dst);
    edge_alpha<<<NN / 4, 256, 0, stream>>>(a_src, a_dst, row_ptr, colidx, alpha);
    aggregate_x<<<NN / 4, 256, 0, stream>>>(xb, alpha, row_ptr, colidx, aggX);
    gemm_out<<<ogrid, 256, 0, stream>>>(aggX, Bt2b, b2, agg, NN);
    hipMemsetAsync(stats, 0, 256 * 4, stream);
    bn_stats<<<200, 256, 0, stream>>>(agg, stats);
    bn_apply<<<(NN * DF + 255) / 256, 256, 0, stream>>>(agg, stats, g2, be2, out);
}

// Round 10
// 433.183 us; speedup vs baseline: 1.1446x; 1.0528x over previous
//
#include <hip/hip_runtime.h>
#include <hip/hip_bf16.h>
#include <hip/hip_fp16.h>
#include <math.h>

#define NN 50000
#define NP 50048            // NN padded to 64-row tiles
#define NE 800000
#define ET (NE + NN)
#define DF 128
#define NH 4
#define HD 512
#define BN_EPS 1e-5f

typedef __hip_bfloat16 bf16;
typedef __attribute__((ext_vector_type(8))) short bf16x8;
typedef __attribute__((ext_vector_type(4))) float f32x4;

// ---------- input conversions ----------
__global__ __launch_bounds__(256) void cvt_x_bf16(const float* __restrict__ in, bf16* __restrict__ out) {
    int i = blockIdx.x * 256 + threadIdx.x;            // 4 elements per thread
    if (i >= NN * DF / 4) return;
    float4 v = reinterpret_cast<const float4*>(in)[i];
    union { bf16 b[4]; short4 s; } u;
    u.b[0] = __float2bfloat16(v.x); u.b[1] = __float2bfloat16(v.y);
    u.b[2] = __float2bfloat16(v.z); u.b[3] = __float2bfloat16(v.w);
    reinterpret_cast<short4*>(out)[i] = u.s;
}

// wsd[layer][o][d] = sum_c W[d, h*128+c] * att[h][c],  o=h (src, 0..3) or 4+h (dst)
__global__ __launch_bounds__(256) void make_wsd(const float* __restrict__ W1, const float* __restrict__ as1,
                                                const float* __restrict__ ad1,
                                                const float* __restrict__ W2, const float* __restrict__ as2,
                                                const float* __restrict__ ad2,
                                                float* __restrict__ wsd) {
    int t = blockIdx.x * 256 + threadIdx.x;   // 0..2047
    if (t >= 2048) return;
    int layer = t >> 10;
    int o = (t >> 7) & 7;
    int d = t & 127;
    int h = o & 3;
    const float* W  = layer ? W2 : W1;
    const float* av = layer ? (o < 4 ? as2 : ad2) : (o < 4 ? as1 : ad1);
    const float* wrow = W + d * HD + h * DF;
    const float* arow = av + h * DF;
    float sum = 0.f;
    for (int c = 0; c < DF; ++c) sum += wrow[c] * arow[c];
    wsd[layer * 1024 + o * DF + d] = sum;
}

// Bt2[layer][c][h*128+d] = 0.25 * W[d][h*128+c]   (stacked, transposed, head-mean folded)
__global__ __launch_bounds__(256) void cvt_bt2(const float* __restrict__ W1, const float* __restrict__ W2,
                                               bf16* __restrict__ B1, bf16* __restrict__ B2) {
    int i = blockIdx.x * 256 + threadIdx.x;   // 0..131071
    if (i >= 2 * DF * HD) return;
    int layer = i >> 16;
    int ii = i & 65535;
    int c = ii >> 9, k = ii & 511;
    int h = k >> 7, d = k & 127;
    const float* W = layer ? W2 : W1;
    bf16* B = layer ? B2 : B1;
    B[ii] = __float2bfloat16(0.25f * W[d * HD + h * DF + c]);
}

// ---------- per-node scores from x: a[n,o] = <x[n], wsd[o]> ----------
__global__ __launch_bounds__(256) void xscore(const bf16* __restrict__ X,
                                              const float* __restrict__ wsd,   // [8][128]
                                              float* __restrict__ a_src,
                                              float* __restrict__ a_dst) {
    __shared__ float w[8][DF];
    reinterpret_cast<float4*>(&w[0][0])[threadIdx.x] = reinterpret_cast<const float4*>(wsd)[threadIdx.x];
    __syncthreads();
    const int n = blockIdx.x * 4 + (threadIdx.x >> 6);
    const int l = threadIdx.x & 63;          // lane owns features 2l, 2l+1
    unsigned xv = reinterpret_cast<const unsigned*>(X)[n * 64 + l];
    float x0 = __uint_as_float(xv << 16);
    float x1 = __uint_as_float(xv & 0xffff0000u);
    float v[8];
    #pragma unroll
    for (int o = 0; o < 8; ++o)
        v[o] = x0 * w[o][2 * l] + x1 * w[o][2 * l + 1];
    #pragma unroll
    for (int off = 1; off < 64; off <<= 1) {
        #pragma unroll
        for (int o = 0; o < 8; ++o) v[o] += __shfl_xor(v[o], off);
    }
    if (l == 0) {
        reinterpret_cast<float4*>(a_src)[n] = make_float4(v[0], v[1], v[2], v[3]);
        reinterpret_cast<float4*>(a_dst)[n] = make_float4(v[4], v[5], v[6], v[7]);
    }
}

// ---------- CSR build: single atomic pass (rank trick) ----------
__global__ __launch_bounds__(256) void count_rank(const int* __restrict__ ei, int* __restrict__ counts,
                                                  int* __restrict__ rank) {
    int e = (blockIdx.x * 256 + threadIdx.x) * 2;
    if (e >= ET) return;
    int d0, d1;
    if (e + 1 < NE) {
        int2 dd = *reinterpret_cast<const int2*>(ei + NE + e);
        d0 = dd.x; d1 = dd.y;
    } else {
        d0 = (e < NE) ? ei[NE + e] : (e - NE);
        d1 = (e + 1 < NE) ? ei[NE + e + 1] : (e + 1 - NE);
    }
    rank[e]     = atomicAdd(&counts[d0 << 4], 1);
    rank[e + 1] = atomicAdd(&counts[d1 << 4], 1);
}

__global__ __launch_bounds__(256) void scan1(const int* __restrict__ counts, int* __restrict__ bsum) {
    __shared__ int sd[256];
    int i = blockIdx.x * 256 + threadIdx.x;
    sd[threadIdx.x] = (i < NN) ? counts[i << 4] : 0;
    __syncthreads();
    for (int s = 128; s > 0; s >>= 1) {
        if (threadIdx.x < s) sd[threadIdx.x] += sd[threadIdx.x + s];
        __syncthreads();
    }
    if (threadIdx.x == 0) bsum[blockIdx.x] = sd[0];
}

// parallel exclusive scan over <=256 block sums (Hillis-Steele)
__global__ __launch_bounds__(256) void scan2(int* __restrict__ bsum, int nb) {
    __shared__ int sd[256];
    int i = threadIdx.x;
    int v = (i < nb) ? bsum[i] : 0;
    sd[i] = v;
    __syncthreads();
    for (int s = 1; s < 256; s <<= 1) {
        int t = sd[i];
        int u = (i >= s) ? sd[i - s] : 0;
        __syncthreads();
        sd[i] = t + u;
        __syncthreads();
    }
    if (i < nb) bsum[i] = sd[i] - v;
}

__global__ __launch_bounds__(256) void scan3(const int* __restrict__ counts, const int* __restrict__ bsum,
                                             int* __restrict__ row_ptr) {
    __shared__ int sd[256];
    int i = blockIdx.x * 256 + threadIdx.x;
    int v = (i < NN) ? counts[i << 4] : 0;
    sd[threadIdx.x] = v;
    __syncthreads();
    for (int s = 1; s < 256; s <<= 1) {
        int t = sd[threadIdx.x];
        int u = (threadIdx.x >= s) ? sd[threadIdx.x - s] : 0;
        __syncthreads();
        sd[threadIdx.x] = t + u;
        __syncthreads();
    }
    int excl = sd[threadIdx.x] - v + bsum[blockIdx.x];
    if (i < NN) row_ptr[i] = excl;
    if (i == 0) row_ptr[NN] = ET;
}

// non-atomic scatter: col[row_ptr[d] + rank[e]] = src(e)
__global__ __launch_bounds__(256) void fill_scatter(const int* __restrict__ ei, const int* __restrict__ rank,
                                                    const int* __restrict__ row_ptr, int* __restrict__ col) {
    int e = (blockIdx.x * 256 + threadIdx.x) * 2;
    if (e >= ET) return;
    int s0, d0, s1, d1;
    if (e + 1 < NE) {
        int2 ss = *reinterpret_cast<const int2*>(ei + e);
        int2 dd = *reinterpret_cast<const int2*>(ei + NE + e);
        s0 = ss.x; s1 = ss.y; d0 = dd.x; d1 = dd.y;
    } else {
        if (e < NE) { s0 = ei[e]; d0 = ei[NE + e]; } else { s0 = d0 = e - NE; }
        if (e + 1 < NE) { s1 = ei[e + 1]; d1 = ei[NE + e + 1]; } else { s1 = d1 = e + 1 - NE; }
    }
    int2 rk = *reinterpret_cast<const int2*>(rank + e);
    col[row_ptr[d0] + rk.x] = s0;
    col[row_ptr[d1] + rk.y] = s1;
}

// ---------- fused softmax + head-weighted x gather (wave per node, flash-style) ----------
// aggX[n][h*128+d] = sum_e softmax_alpha[e,h] * x[src(e), d]
__global__ __launch_bounds__(256) void agg_fused(const bf16* __restrict__ X,
                                                 const float* __restrict__ a_src,
                                                 const float* __restrict__ a_dst,
                                                 const int* __restrict__ row_ptr,
                                                 const int* __restrict__ col,
                                                 bf16* __restrict__ aggX) {
    const int n = blockIdx.x * 4 + (threadIdx.x >> 6);
    const int l = threadIdx.x & 63;          // lane owns x features 2l, 2l+1
    const int start = row_ptr[n], end = row_ptr[n + 1];
    const float4 ad4 = reinterpret_cast<const float4*>(a_dst)[n];
    const float4* __restrict__ as4 = reinterpret_cast<const float4*>(a_src);
    const unsigned* __restrict__ X4 = reinterpret_cast<const unsigned*>(X);
    float m[4] = {-1e30f, -1e30f, -1e30f, -1e30f};
    float s[4] = {0.f, 0.f, 0.f, 0.f};
    float acc[4][2] = {};
    for (int base = start; base < end; base += 64) {
        const int j = base + l;
        const bool valid = j < end;
        const int cj = valid ? col[j] : 0;
        float lv[4] = {-1e30f, -1e30f, -1e30f, -1e30f};
        if (valid) {
            float4 a = as4[cj];
            lv[0] = a.x + ad4.x; lv[1] = a.y + ad4.y; lv[2] = a.z + ad4.z; lv[3] = a.w + ad4.w;
            #pragma unroll
            for (int h = 0; h < 4; ++h) lv[h] = lv[h] > 0.f ? lv[h] : 0.2f * lv[h];
        }
        float cm[4];
        #pragma unroll
        for (int h = 0; h < 4; ++h) cm[h] = lv[h];
        #pragma unroll
        for (int off = 1; off < 64; off <<= 1) {
            #pragma unroll
            for (int h = 0; h < 4; ++h) cm[h] = fmaxf(cm[h], __shfl_xor(cm[h], off));
        }
        float p[4], ps[4];
        #pragma unroll
        for (int h = 0; h < 4; ++h) {
            float nm = fmaxf(m[h], cm[h]);
            float sc = __expf(m[h] - nm);        // first chunk: exp(-huge)=0
            p[h] = valid ? __expf(lv[h] - nm) : 0.f;
            s[h] *= sc;
            acc[h][0] *= sc; acc[h][1] *= sc;
            m[h] = nm;
            ps[h] = p[h];
        }
        #pragma unroll
        for (int off = 1; off < 64; off <<= 1) {
            #pragma unroll
            for (int h = 0; h < 4; ++h) ps[h] += __shfl_xor(ps[h], off);
        }
        #pragma unroll
        for (int h = 0; h < 4; ++h) s[h] += ps[h];
        const int cnt = min(64, end - base);
        for (int e = 0; e < cnt; e += 4) {
            #pragma unroll
            for (int u = 0; u < 4; ++u) {
                int ee = e + u;                  // lanes >= cnt carry p=0, cj=0 -> contribute 0
                int src = __shfl(cj, ee);
                float b0 = __shfl(p[0], ee);
                float b1 = __shfl(p[1], ee);
                float b2 = __shfl(p[2], ee);
                float b3 = __shfl(p[3], ee);
                unsigned xv = X4[(size_t)src * 64 + l];
                float lo = __uint_as_float(xv << 16);
                float hi = __uint_as_float(xv & 0xffff0000u);
                acc[0][0] += b0 * lo; acc[0][1] += b0 * hi;
                acc[1][0] += b1 * lo; acc[1][1] += b1 * hi;
                acc[2][0] += b2 * lo; acc[2][1] += b2 * hi;
                acc[3][0] += b3 * lo; acc[3][1] += b3 * hi;
            }
        }
    }
    unsigned* outp = reinterpret_cast<unsigned*>(aggX) + (size_t)n * 256;
    #pragma unroll
    for (int h = 0; h < 4; ++h) {
        float inv = 1.f / s[h];
        union { bf16 b; unsigned short u; } plo, phi;
        plo.b = __float2bfloat16(acc[h][0] * inv);
        phi.b = __float2bfloat16(acc[h][1] * inv);
        outp[h * 64 + l] = (unsigned)plo.u | ((unsigned)phi.u << 16);
    }
}

// ---------- MFMA GEMM: out[M,128](f32) = A[M,512](bf16) @ Bt[128,512]^T + bias ----------
// Fused BN-stats epilogue: per-block LDS column sums -> global atomics into stats[256].
__global__ __launch_bounds__(256) void gemm_out(const bf16* __restrict__ A,
                                                const bf16* __restrict__ Bt,
                                                const float* __restrict__ bias,
                                                float* __restrict__ out,
                                                float* __restrict__ stats, int M) {
    __shared__ __align__(16) char As[2][16384];   // [64 rows][256B k-chunk], XOR-swizzled
    __shared__ __align__(16) char Bs[2][16384];
    __shared__ float ssum[64], ssq[64];
    const int tid = threadIdx.x;
    if (tid < 64) { ssum[tid] = 0.f; ssq[tid] = 0.f; }
    const int m0 = blockIdx.x * 64;
    const int n0 = blockIdx.y * 64;
    const char* Ab = (const char*)A + (size_t)m0 * 1024;     // row stride 512*2 B
    const char* Bb = (const char*)Bt + (size_t)n0 * 1024;
    auto stage = [&](const char* base, char* lds, int kc) {
        #pragma unroll
        for (int i = 0; i < 4; ++i) {
            int d = (tid + i * 256) * 16;
            int row = d >> 8;
            int sw = (d & 255) ^ ((row & 7) << 4);
            __builtin_amdgcn_global_load_lds(
                (const __attribute__((address_space(1))) void*)(base + (size_t)row * 1024 + kc * 256 + sw),
                (__attribute__((address_space(3))) void*)(lds + d), 16, 0, 0);
        }
    };
    stage(Ab, As[0], 0);
    stage(Bb, Bs[0], 0);
    const int lane = tid & 63;
    const int wave = tid >> 6;
    const int wm = (wave & 1) * 32;
    const int wn = (wave >> 1) * 32;
    const int lr = lane & 15;
    const int lkb = (lane >> 4) * 16;
    f32x4 acc[2][2] = {};
    for (int kc = 0; kc < 4; ++kc) {
        __syncthreads();
        if (kc < 3) {
            stage(Ab, As[(kc + 1) & 1], kc + 1);
            stage(Bb, Bs[(kc + 1) & 1], kc + 1);
        }
        const char* Ac = As[kc & 1];
        const char* Bc = Bs[kc & 1];
        #pragma unroll
        for (int kk = 0; kk < 4; ++kk) {
            int kb = kk * 64 + lkb;
            int ra0 = wm + lr, ra1 = wm + 16 + lr;
            int rb0 = wn + lr, rb1 = wn + 16 + lr;
            bf16x8 a0 = *(const bf16x8*)(Ac + ((ra0 * 256 + kb) ^ ((ra0 & 7) << 4)));
            bf16x8 a1 = *(const bf16x8*)(Ac + ((ra1 * 256 + kb) ^ ((ra1 & 7) << 4)));
            bf16x8 b0 = *(const bf16x8*)(Bc + ((rb0 * 256 + kb) ^ ((rb0 & 7) << 4)));
            bf16x8 b1 = *(const bf16x8*)(Bc + ((rb1 * 256 + kb) ^ ((rb1 & 7) << 4)));
            acc[0][0] = __builtin_amdgcn_mfma_f32_16x16x32_bf16(a0, b0, acc[0][0], 0, 0, 0);
            acc[0][1] = __builtin_amdgcn_mfma_f32_16x16x32_bf16(a0, b1, acc[0][1], 0, 0, 0);
            acc[1][0] = __builtin_amdgcn_mfma_f32_16x16x32_bf16(a1, b0, acc[1][0], 0, 0, 0);
            acc[1][1] = __builtin_amdgcn_mfma_f32_16x16x32_bf16(a1, b1, acc[1][1], 0, 0, 0);
        }
    }
    const int orow = (lane >> 4) * 4;
    float bcol[2];
    bcol[0] = bias[n0 + wn + lr];
    bcol[1] = bias[n0 + wn + 16 + lr];
    #pragma unroll
    for (int ni = 0; ni < 2; ++ni) {
        float cs = 0.f, cq = 0.f;
        #pragma unroll
        for (int mi = 0; mi < 2; ++mi) {
            #pragma unroll
            for (int r = 0; r < 4; ++r) {
                int gr = m0 + wm + mi * 16 + orow + r;
                if (gr < M) {
                    float v = acc[mi][ni][r] + bcol[ni];
                    out[(size_t)gr * DF + n0 + wn + ni * 16 + lr] = v;
                    cs += v; cq += v * v;
                }
            }
        }
        atomicAdd(&ssum[wn + ni * 16 + lr], cs);
        atomicAdd(&ssq[wn + ni * 16 + lr], cq);
    }
    __syncthreads();
    if (tid < 64) {
        atomicAdd(&stats[n0 + tid], ssum[tid]);
        atomicAdd(&stats[128 + n0 + tid], ssq[tid]);
    }
}

// ---------- BatchNorm apply ----------
__global__ __launch_bounds__(256) void bn_apply_bf16(const float* __restrict__ x, const float* __restrict__ stats,
                                                     const float* __restrict__ gamma, const float* __restrict__ beta,
                                                     bf16* __restrict__ out) {
    int i = blockIdx.x * blockDim.x + threadIdx.x;
    if (i >= NN * DF) return;
    int c = i & 127;
    float mu = stats[c] * (1.f / NN);
    float var = stats[128 + c] * (1.f / NN) - mu * mu;
    float v = (x[i] - mu) * rsqrtf(var + BN_EPS) * gamma[c] + beta[c];
    out[i] = __float2bfloat16(fmaxf(v, 0.f));
}

__global__ __launch_bounds__(256) void bn_apply(const float* __restrict__ x, const float* __restrict__ stats,
                                                const float* __restrict__ gamma, const float* __restrict__ beta,
                                                float* __restrict__ out) {
    int i = blockIdx.x * blockDim.x + threadIdx.x;
    if (i >= NN * DF) return;
    int c = i & 127;
    float mu = stats[c] * (1.f / NN);
    float var = stats[128 + c] * (1.f / NN) - mu * mu;
    float v = (x[i] - mu) * rsqrtf(var + BN_EPS) * gamma[c] + beta[c];
    out[i] = fmaxf(v, 0.f);
}

extern "C" void kernel_launch(void* const* d_in, const int* in_sizes, int n_in,
                              void* d_out, int out_size, void* d_ws, size_t ws_size,
                              hipStream_t stream) {
    (void)in_sizes; (void)n_in; (void)out_size; (void)ws_size;
    const float* x   = (const float*)d_in[0];
    const int*   ei  = (const int*)d_in[1];
    const float* W1  = (const float*)d_in[2];
    const float* as1 = (const float*)d_in[3];
    const float* ad1 = (const float*)d_in[4];
    const float* b1  = (const float*)d_in[5];
    const float* g1  = (const float*)d_in[6];
    const float* be1 = (const float*)d_in[7];
    const float* W2  = (const float*)d_in[8];
    const float* as2 = (const float*)d_in[9];
    const float* ad2 = (const float*)d_in[10];
    const float* b2  = (const float*)d_in[11];
    const float* g2  = (const float*)d_in[12];
    const float* be2 = (const float*)d_in[13];
    float* out = (float*)d_out;

    char* ws = (char*)d_ws;
    size_t off = 0;
    auto alloc = [&](size_t bytes) -> void* {
        void* p = ws + off;
        off += (bytes + 255) & ~(size_t)255;
        return p;
    };
    bf16*   aggX    = (bf16*)alloc((size_t)NP * HD * 2);      // 51.25 MB
    bf16*   xb      = (bf16*)alloc((size_t)NP * DF * 2);      // 12.8 MB (padded)
    bf16*   Bt2a    = (bf16*)alloc((size_t)DF * HD * 2);      // 128 KB
    bf16*   Bt2b    = (bf16*)alloc((size_t)DF * HD * 2);
    float*  wsd     = (float*)alloc(2 * 1024 * 4);            // 8 KB
    float*  a_src   = (float*)alloc((size_t)NN * NH * 4);
    float*  a_dst   = (float*)alloc((size_t)NN * NH * 4);
    int*    row_ptr = (int*)alloc((size_t)(NN + 1) * 4);
    int*    bsum    = (int*)alloc(256 * 4);
    int*    colidx  = (int*)alloc((size_t)ET * 4);
    float*  agg     = (float*)alloc((size_t)NN * DF * 4);     // 25.6 MB
    float*  stats   = (float*)alloc(256 * 4);
    // counts (padded 64B/dst, 3.2MB) + rank (3.4MB) aliased into agg
    // (agg is first written by gemm_out, long after CSR build completes)
    int*    counts  = (int*)agg;
    int*    rank    = (int*)((char*)agg + ((size_t)NP << 6));
    // high-water ~95 MB (<= R1-proven 107.4 MB)

    const int NB = (NN + 255) / 256;        // 196
    const int EB2 = (ET / 2 + 255) / 256;   // 1661
    dim3 ogrid(NP / 64, 2);                 // 782 x 2

    // ---- prep + CSR build (single atomic pass) ----
    cvt_x_bf16<<<(NN * DF / 4 + 255) / 256, 256, 0, stream>>>(x, xb);
    make_wsd<<<8, 256, 0, stream>>>(W1, as1, ad1, W2, as2, ad2, wsd);
    cvt_bt2<<<(2 * DF * HD + 255) / 256, 256, 0, stream>>>(W1, W2, Bt2a, Bt2b);
    hipMemsetAsync(counts, 0, (size_t)NP << 6, stream);
    count_rank<<<EB2, 256, 0, stream>>>(ei, counts, rank);
    scan1<<<NB, 256, 0, stream>>>(counts, bsum);
    scan2<<<1, 256, 0, stream>>>(bsum, NB);
    scan3<<<NB, 256, 0, stream>>>(counts, bsum, row_ptr);
    fill_scatter<<<EB2, 256, 0, stream>>>(ei, rank, row_ptr, colidx);

    // ---- layer 1 ----
    xscore<<<NN / 4, 256, 0, stream>>>(xb, wsd, a_src, a_dst);
    agg_fused<<<NN / 4, 256, 0, stream>>>(xb, a_src, a_dst, row_ptr, colidx, aggX);
    hipMemsetAsync(stats, 0, 256 * 4, stream);
    gemm_out<<<ogrid, 256, 0, stream>>>(aggX, Bt2a, b1, agg, stats, NN);
    bn_apply_bf16<<<(NN * DF + 255) / 256, 256, 0, stream>>>(agg, stats, g1, be1, xb);

    // ---- layer 2 ----
    xscore<<<NN / 4, 256, 0, stream>>>(xb, wsd + 1024, a_src, a_dst);
    agg_fused<<<NN / 4, 256, 0, stream>>>(xb, a_src, a_dst, row_ptr, colidx, aggX);
    hipMemsetAsync(stats, 0, 256 * 4, stream);
    gemm_out<<<ogrid, 256, 0, stream>>>(aggX, Bt2b, b2, agg, stats, NN);
    bn_apply<<<(NN * DF + 255) / 256, 256, 0, stream>>>(agg, stats, g2, be2, out);
}

// Round 11
// 425.080 us; speedup vs baseline: 1.1664x; 1.0191x over previous
//
#include <hip/hip_runtime.h>
#include <hip/hip_bf16.h>
#include <hip/hip_fp16.h>
#include <math.h>

#define NN 50000
#define NP 50048            // NN padded to 64-row tiles
#define NE 800000
#define ET (NE + NN)
#define DF 128
#define NH 4
#define HD 512
#define BN_EPS 1e-5f

typedef __hip_bfloat16 bf16;
typedef __attribute__((ext_vector_type(8))) short bf16x8;
typedef __attribute__((ext_vector_type(4))) float f32x4;

struct alignas(8) h2x2 { __half2 a, b; };

// ---------- input conversions ----------
__global__ __launch_bounds__(256) void cvt_x_bf16(const float* __restrict__ in, bf16* __restrict__ out) {
    int i = blockIdx.x * 256 + threadIdx.x;            // 4 elements per thread
    if (i >= NN * DF / 4) return;
    float4 v = reinterpret_cast<const float4*>(in)[i];
    union { bf16 b[4]; short4 s; } u;
    u.b[0] = __float2bfloat16(v.x); u.b[1] = __float2bfloat16(v.y);
    u.b[2] = __float2bfloat16(v.z); u.b[3] = __float2bfloat16(v.w);
    reinterpret_cast<short4*>(out)[i] = u.s;
}

// wsd[layer][o][d] = sum_c W[d, h*128+c] * att[h][c],  o=h (src, 0..3) or 4+h (dst)
__global__ __launch_bounds__(256) void make_wsd(const float* __restrict__ W1, const float* __restrict__ as1,
                                                const float* __restrict__ ad1,
                                                const float* __restrict__ W2, const float* __restrict__ as2,
                                                const float* __restrict__ ad2,
                                                float* __restrict__ wsd) {
    int t = blockIdx.x * 256 + threadIdx.x;   // 0..2047
    if (t >= 2048) return;
    int layer = t >> 10;
    int o = (t >> 7) & 7;
    int d = t & 127;
    int h = o & 3;
    const float* W  = layer ? W2 : W1;
    const float* av = layer ? (o < 4 ? as2 : ad2) : (o < 4 ? as1 : ad1);
    const float* wrow = W + d * HD + h * DF;
    const float* arow = av + h * DF;
    float sum = 0.f;
    for (int c = 0; c < DF; ++c) sum += wrow[c] * arow[c];
    wsd[layer * 1024 + o * DF + d] = sum;
}

// Bt2[layer][c][h*128+d] = 0.25 * W[d][h*128+c]   (stacked, transposed, head-mean folded)
__global__ __launch_bounds__(256) void cvt_bt2(const float* __restrict__ W1, const float* __restrict__ W2,
                                               bf16* __restrict__ B1, bf16* __restrict__ B2) {
    int i = blockIdx.x * 256 + threadIdx.x;   // 0..131071
    if (i >= 2 * DF * HD) return;
    int layer = i >> 16;
    int ii = i & 65535;
    int c = ii >> 9, k = ii & 511;
    int h = k >> 7, d = k & 127;
    const float* W = layer ? W2 : W1;
    bf16* B = layer ? B2 : B1;
    B[ii] = __float2bfloat16(0.25f * W[d * HD + h * DF + c]);
}

// ---------- per-node scores from x: a[n,o] = <x[n], wsd[o]> ----------
__global__ __launch_bounds__(256) void xscore(const bf16* __restrict__ X,
                                              const float* __restrict__ wsd,   // [8][128]
                                              float* __restrict__ a_src,
                                              float* __restrict__ a_dst) {
    __shared__ float w[8][DF];
    reinterpret_cast<float4*>(&w[0][0])[threadIdx.x] = reinterpret_cast<const float4*>(wsd)[threadIdx.x];
    __syncthreads();
    const int n = blockIdx.x * 4 + (threadIdx.x >> 6);
    const int l = threadIdx.x & 63;          // lane owns features 2l, 2l+1
    unsigned xv = reinterpret_cast<const unsigned*>(X)[n * 64 + l];
    float x0 = __uint_as_float(xv << 16);
    float x1 = __uint_as_float(xv & 0xffff0000u);
    float v[8];
    #pragma unroll
    for (int o = 0; o < 8; ++o)
        v[o] = x0 * w[o][2 * l] + x1 * w[o][2 * l + 1];
    #pragma unroll
    for (int off = 1; off < 64; off <<= 1) {
        #pragma unroll
        for (int o = 0; o < 8; ++o) v[o] += __shfl_xor(v[o], off);
    }
    if (l == 0) {
        reinterpret_cast<float4*>(a_src)[n] = make_float4(v[0], v[1], v[2], v[3]);
        reinterpret_cast<float4*>(a_dst)[n] = make_float4(v[4], v[5], v[6], v[7]);
    }
}

// ---------- CSR build: single atomic pass (rank trick) ----------
__global__ __launch_bounds__(256) void count_rank(const int* __restrict__ ei, int* __restrict__ counts,
                                                  int* __restrict__ rank) {
    int e = (blockIdx.x * 256 + threadIdx.x) * 2;
    if (e >= ET) return;
    int d0, d1;
    if (e + 1 < NE) {
        int2 dd = *reinterpret_cast<const int2*>(ei + NE + e);
        d0 = dd.x; d1 = dd.y;
    } else {
        d0 = (e < NE) ? ei[NE + e] : (e - NE);
        d1 = (e + 1 < NE) ? ei[NE + e + 1] : (e + 1 - NE);
    }
    rank[e]     = atomicAdd(&counts[d0 << 4], 1);
    rank[e + 1] = atomicAdd(&counts[d1 << 4], 1);
}

__global__ __launch_bounds__(256) void scan1(const int* __restrict__ counts, int* __restrict__ bsum) {
    __shared__ int sd[256];
    int i = blockIdx.x * 256 + threadIdx.x;
    sd[threadIdx.x] = (i < NN) ? counts[i << 4] : 0;
    __syncthreads();
    for (int s = 128; s > 0; s >>= 1) {
        if (threadIdx.x < s) sd[threadIdx.x] += sd[threadIdx.x + s];
        __syncthreads();
    }
    if (threadIdx.x == 0) bsum[blockIdx.x] = sd[0];
}

// parallel exclusive scan over <=256 block sums (Hillis-Steele)
__global__ __launch_bounds__(256) void scan2(int* __restrict__ bsum, int nb) {
    __shared__ int sd[256];
    int i = threadIdx.x;
    int v = (i < nb) ? bsum[i] : 0;
    sd[i] = v;
    __syncthreads();
    for (int s = 1; s < 256; s <<= 1) {
        int t = sd[i];
        int u = (i >= s) ? sd[i - s] : 0;
        __syncthreads();
        sd[i] = t + u;
        __syncthreads();
    }
    if (i < nb) bsum[i] = sd[i] - v;
}

__global__ __launch_bounds__(256) void scan3(const int* __restrict__ counts, const int* __restrict__ bsum,
                                             int* __restrict__ row_ptr) {
    __shared__ int sd[256];
    int i = blockIdx.x * 256 + threadIdx.x;
    int v = (i < NN) ? counts[i << 4] : 0;
    sd[threadIdx.x] = v;
    __syncthreads();
    for (int s = 1; s < 256; s <<= 1) {
        int t = sd[threadIdx.x];
        int u = (threadIdx.x >= s) ? sd[threadIdx.x - s] : 0;
        __syncthreads();
        sd[threadIdx.x] = t + u;
        __syncthreads();
    }
    int excl = sd[threadIdx.x] - v + bsum[blockIdx.x];
    if (i < NN) row_ptr[i] = excl;
    if (i == 0) row_ptr[NN] = ET;
}

// non-atomic scatter: col[row_ptr[d] + rank[e]] = src(e)
__global__ __launch_bounds__(256) void fill_scatter(const int* __restrict__ ei, const int* __restrict__ rank,
                                                    const int* __restrict__ row_ptr, int* __restrict__ col) {
    int e = (blockIdx.x * 256 + threadIdx.x) * 2;
    if (e >= ET) return;
    int s0, d0, s1, d1;
    if (e + 1 < NE) {
        int2 ss = *reinterpret_cast<const int2*>(ei + e);
        int2 dd = *reinterpret_cast<const int2*>(ei + NE + e);
        s0 = ss.x; s1 = ss.y; d0 = dd.x; d1 = dd.y;
    } else {
        if (e < NE) { s0 = ei[e]; d0 = ei[NE + e]; } else { s0 = d0 = e - NE; }
        if (e + 1 < NE) { s1 = ei[e + 1]; d1 = ei[NE + e + 1]; } else { s1 = d1 = e + 1 - NE; }
    }
    int2 rk = *reinterpret_cast<const int2*>(rank + e);
    col[row_ptr[d0] + rk.x] = s0;
    col[row_ptr[d1] + rk.y] = s1;
}

// ---------- per-edge alpha: one WAVE per node, single gather pass ----------
__global__ __launch_bounds__(256) void edge_alpha(const float* __restrict__ a_src,
                                                  const float* __restrict__ a_dst,
                                                  const int* __restrict__ row_ptr,
                                                  const int* __restrict__ col,
                                                  __half* __restrict__ alpha) {
    const int n = blockIdx.x * 4 + (threadIdx.x >> 6);
    const int l = threadIdx.x & 63;
    const int start = row_ptr[n], end = row_ptr[n + 1];
    const float4 ad4 = reinterpret_cast<const float4*>(a_dst)[n];
    const float4* __restrict__ as4 = reinterpret_cast<const float4*>(a_src);
    if (end - start <= 64) {                       // common case: deg <= 64
        const int j = start + l;
        float lv[4] = {-1e30f, -1e30f, -1e30f, -1e30f};
        if (j < end) {
            float4 a = as4[col[j]];
            lv[0] = a.x + ad4.x; lv[1] = a.y + ad4.y; lv[2] = a.z + ad4.z; lv[3] = a.w + ad4.w;
            #pragma unroll
            for (int h = 0; h < 4; ++h) lv[h] = lv[h] > 0.f ? lv[h] : 0.2f * lv[h];
        }
        float m[4], p[4], s[4];
        #pragma unroll
        for (int h = 0; h < 4; ++h) m[h] = lv[h];
        #pragma unroll
        for (int off = 1; off < 64; off <<= 1) {
            #pragma unroll
            for (int h = 0; h < 4; ++h) m[h] = fmaxf(m[h], __shfl_xor(m[h], off));
        }
        #pragma unroll
        for (int h = 0; h < 4; ++h) { p[h] = (j < end) ? __expf(lv[h] - m[h]) : 0.f; s[h] = p[h]; }
        #pragma unroll
        for (int off = 1; off < 64; off <<= 1) {
            #pragma unroll
            for (int h = 0; h < 4; ++h) s[h] += __shfl_xor(s[h], off);
        }
        if (j < end) {
            h2x2 o;
            o.a = __floats2half2_rn(p[0] / s[0], p[1] / s[1]);
            o.b = __floats2half2_rn(p[2] / s[2], p[3] / s[3]);
            reinterpret_cast<h2x2*>(alpha)[j] = o;
        }
    } else {                                       // rare: deg > 64, chunked online
        float m[4] = {-1e30f, -1e30f, -1e30f, -1e30f}, s[4] = {0.f, 0.f, 0.f, 0.f};
        for (int base = start; base < end; base += 64) {
            const int j = base + l;
            float lv[4] = {-1e30f, -1e30f, -1e30f, -1e30f};
            if (j < end) {
                float4 a = as4[col[j]];
                lv[0] = a.x + ad4.x; lv[1] = a.y + ad4.y; lv[2] = a.z + ad4.z; lv[3] = a.w + ad4.w;
                #pragma unroll
                for (int h = 0; h < 4; ++h) lv[h] = lv[h] > 0.f ? lv[h] : 0.2f * lv[h];
            }
            float cm[4], cp[4];
            #pragma unroll
            for (int h = 0; h < 4; ++h) cm[h] = lv[h];
            #pragma unroll
            for (int off = 1; off < 64; off <<= 1) {
                #pragma unroll
                for (int h = 0; h < 4; ++h) cm[h] = fmaxf(cm[h], __shfl_xor(cm[h], off));
            }
            #pragma unroll
            for (int h = 0; h < 4; ++h) {
                float nm = fmaxf(m[h], cm[h]);
                cp[h] = (j < end) ? __expf(lv[h] - nm) : 0.f;
                s[h] *= __expf(m[h] - nm);
                m[h] = nm;
            }
            #pragma unroll
            for (int off = 1; off < 64; off <<= 1) {
                #pragma unroll
                for (int h = 0; h < 4; ++h) cp[h] += __shfl_xor(cp[h], off);
            }
            #pragma unroll
            for (int h = 0; h < 4; ++h) s[h] += cp[h];
        }
        for (int base = start; base < end; base += 64) {
            const int j = base + l;
            if (j < end) {
                float4 a = as4[col[j]];
                float v0 = a.x + ad4.x, v1 = a.y + ad4.y, v2 = a.z + ad4.z, v3 = a.w + ad4.w;
                v0 = v0 > 0.f ? v0 : 0.2f * v0; v1 = v1 > 0.f ? v1 : 0.2f * v1;
                v2 = v2 > 0.f ? v2 : 0.2f * v2; v3 = v3 > 0.f ? v3 : 0.2f * v3;
                h2x2 o;
                o.a = __floats2half2_rn(__expf(v0 - m[0]) / s[0], __expf(v1 - m[1]) / s[1]);
                o.b = __floats2half2_rn(__expf(v2 - m[2]) / s[2], __expf(v3 - m[3]) / s[3]);
                reinterpret_cast<h2x2*>(alpha)[j] = o;
            }
        }
    }
}

// ---------- head-weighted x gather: aggX[n][h*128+d] = sum_e alpha[e,h] x[src,d] ----------
#define EDGE(xu, pu) {                                                               \
    float lo = __uint_as_float((xu) << 16);                                          \
    float hi = __uint_as_float((xu) & 0xffff0000u);                                  \
    float2 f01 = __half22float2(*reinterpret_cast<const __half2*>(&(pu).x));         \
    float2 f23 = __half22float2(*reinterpret_cast<const __half2*>(&(pu).y));         \
    acc[0][0] += f01.x * lo; acc[0][1] += f01.x * hi;                                \
    acc[1][0] += f01.y * lo; acc[1][1] += f01.y * hi;                                \
    acc[2][0] += f23.x * lo; acc[2][1] += f23.x * hi;                                \
    acc[3][0] += f23.y * lo; acc[3][1] += f23.y * hi; }

__global__ __launch_bounds__(256) void aggregate_x(const bf16* __restrict__ X,
                                                   const __half* __restrict__ alpha,
                                                   const int* __restrict__ row_ptr,
                                                   const int* __restrict__ col,
                                                   bf16* __restrict__ aggX) {
    const int n = blockIdx.x * 4 + (threadIdx.x >> 6);
    const int l = threadIdx.x & 63;          // lane owns x features 2l, 2l+1
    const int start = row_ptr[n], end = row_ptr[n + 1];
    const unsigned* __restrict__ X4 = reinterpret_cast<const unsigned*>(X);
    float acc[4][2] = {};
    int j = start;
    for (; j + 4 <= end; j += 4) {
        int c0 = col[j], c1 = col[j + 1], c2 = col[j + 2], c3 = col[j + 3];
        unsigned x0 = X4[c0 * 64 + l];
        unsigned x1 = X4[c1 * 64 + l];
        unsigned x2 = X4[c2 * 64 + l];
        unsigned x3 = X4[c3 * 64 + l];
        uint2 p0 = *reinterpret_cast<const uint2*>(alpha + 4 * j);
        uint2 p1 = *reinterpret_cast<const uint2*>(alpha + 4 * (j + 1));
        uint2 p2 = *reinterpret_cast<const uint2*>(alpha + 4 * (j + 2));
        uint2 p3 = *reinterpret_cast<const uint2*>(alpha + 4 * (j + 3));
        EDGE(x0, p0) EDGE(x1, p1) EDGE(x2, p2) EDGE(x3, p3)
    }
    for (; j < end; ++j) {
        unsigned x0 = X4[col[j] * 64 + l];
        uint2 p0 = *reinterpret_cast<const uint2*>(alpha + 4 * j);
        EDGE(x0, p0)
    }
    unsigned* outp = reinterpret_cast<unsigned*>(aggX) + (size_t)n * 256;
    #pragma unroll
    for (int h = 0; h < 4; ++h) {
        union { bf16 b; unsigned short u; } plo, phi;
        plo.b = __float2bfloat16(acc[h][0]);
        phi.b = __float2bfloat16(acc[h][1]);
        outp[h * 64 + l] = (unsigned)plo.u | ((unsigned)phi.u << 16);
    }
}

// ---------- MFMA GEMM: out[M,128](f32) = A[M,512](bf16) @ Bt[128,512]^T + bias ----------
// Fused BN-stats epilogue: per-block LDS column sums -> global atomics into stats[256].
__global__ __launch_bounds__(256) void gemm_out(const bf16* __restrict__ A,
                                                const bf16* __restrict__ Bt,
                                                const float* __restrict__ bias,
                                                float* __restrict__ out,
                                                float* __restrict__ stats, int M) {
    __shared__ __align__(16) char As[2][16384];   // [64 rows][256B k-chunk], XOR-swizzled
    __shared__ __align__(16) char Bs[2][16384];
    __shared__ float ssum[64], ssq[64];
    const int tid = threadIdx.x;
    if (tid < 64) { ssum[tid] = 0.f; ssq[tid] = 0.f; }
    const int m0 = blockIdx.x * 64;
    const int n0 = blockIdx.y * 64;
    const char* Ab = (const char*)A + (size_t)m0 * 1024;     // row stride 512*2 B
    const char* Bb = (const char*)Bt + (size_t)n0 * 1024;
    auto stage = [&](const char* base, char* lds, int kc) {
        #pragma unroll
        for (int i = 0; i < 4; ++i) {
            int d = (tid + i * 256) * 16;
            int row = d >> 8;
            int sw = (d & 255) ^ ((row & 7) << 4);
            __builtin_amdgcn_global_load_lds(
                (const __attribute__((address_space(1))) void*)(base + (size_t)row * 1024 + kc * 256 + sw),
                (__attribute__((address_space(3))) void*)(lds + d), 16, 0, 0);
        }
    };
    stage(Ab, As[0], 0);
    stage(Bb, Bs[0], 0);
    const int lane = tid & 63;
    const int wave = tid >> 6;
    const int wm = (wave & 1) * 32;
    const int wn = (wave >> 1) * 32;
    const int lr = lane & 15;
    const int lkb = (lane >> 4) * 16;
    f32x4 acc[2][2] = {};
    for (int kc = 0; kc < 4; ++kc) {
        __syncthreads();
        if (kc < 3) {
            stage(Ab, As[(kc + 1) & 1], kc + 1);
            stage(Bb, Bs[(kc + 1) & 1], kc + 1);
        }
        const char* Ac = As[kc & 1];
        const char* Bc = Bs[kc & 1];
        #pragma unroll
        for (int kk = 0; kk < 4; ++kk) {
            int kb = kk * 64 + lkb;
            int ra0 = wm + lr, ra1 = wm + 16 + lr;
            int rb0 = wn + lr, rb1 = wn + 16 + lr;
            bf16x8 a0 = *(const bf16x8*)(Ac + ((ra0 * 256 + kb) ^ ((ra0 & 7) << 4)));
            bf16x8 a1 = *(const bf16x8*)(Ac + ((ra1 * 256 + kb) ^ ((ra1 & 7) << 4)));
            bf16x8 b0 = *(const bf16x8*)(Bc + ((rb0 * 256 + kb) ^ ((rb0 & 7) << 4)));
            bf16x8 b1 = *(const bf16x8*)(Bc + ((rb1 * 256 + kb) ^ ((rb1 & 7) << 4)));
            acc[0][0] = __builtin_amdgcn_mfma_f32_16x16x32_bf16(a0, b0, acc[0][0], 0, 0, 0);
            acc[0][1] = __builtin_amdgcn_mfma_f32_16x16x32_bf16(a0, b1, acc[0][1], 0, 0, 0);
            acc[1][0] = __builtin_amdgcn_mfma_f32_16x16x32_bf16(a1, b0, acc[1][0], 0, 0, 0);
            acc[1][1] = __builtin_amdgcn_mfma_f32_16x16x32_bf16(a1, b1, acc[1][1], 0, 0, 0);
        }
    }
    const int orow = (lane >> 4) * 4;
    float bcol[2];
    bcol[0] = bias[n0 + wn + lr];
    bcol[1] = bias[n0 + wn + 16 + lr];
    #pragma unroll
    for (int ni = 0; ni < 2; ++ni) {
        float cs = 0.f, cq = 0.f;
        #pragma unroll
        for (int mi = 0; mi < 2; ++mi) {
            #pragma unroll
            for (int r = 0; r < 4; ++r) {
                int gr = m0 + wm + mi * 16 + orow + r;
                if (gr < M) {
                    float v = acc[mi][ni][r] + bcol[ni];
                    out[(size_t)gr * DF + n0 + wn + ni * 16 + lr] = v;
                    cs += v; cq += v * v;
                }
            }
        }
        atomicAdd(&ssum[wn + ni * 16 + lr], cs);
        atomicAdd(&ssq[wn + ni * 16 + lr], cq);
    }
    __syncthreads();
    if (tid < 64) {
        atomicAdd(&stats[n0 + tid], ssum[tid]);
        atomicAdd(&stats[128 + n0 + tid], ssq[tid]);
    }
}

// ---------- BatchNorm apply ----------
__global__ __launch_bounds__(256) void bn_apply_bf16(const float* __restrict__ x, const float* __restrict__ stats,
                                                     const float* __restrict__ gamma, const float* __restrict__ beta,
                                                     bf16* __restrict__ out) {
    int i = blockIdx.x * blockDim.x + threadIdx.x;
    if (i >= NN * DF) return;
    int c = i & 127;
    float mu = stats[c] * (1.f / NN);
    float var = stats[128 + c] * (1.f / NN) - mu * mu;
    float v = (x[i] - mu) * rsqrtf(var + BN_EPS) * gamma[c] + beta[c];
    out[i] = __float2bfloat16(fmaxf(v, 0.f));
}

__global__ __launch_bounds__(256) void bn_apply(const float* __restrict__ x, const float* __restrict__ stats,
                                                const float* __restrict__ gamma, const float* __restrict__ beta,
                                                float* __restrict__ out) {
    int i = blockIdx.x * blockDim.x + threadIdx.x;
    if (i >= NN * DF) return;
    int c = i & 127;
    float mu = stats[c] * (1.f / NN);
    float var = stats[128 + c] * (1.f / NN) - mu * mu;
    float v = (x[i] - mu) * rsqrtf(var + BN_EPS) * gamma[c] + beta[c];
    out[i] = fmaxf(v, 0.f);
}

extern "C" void kernel_launch(void* const* d_in, const int* in_sizes, int n_in,
                              void* d_out, int out_size, void* d_ws, size_t ws_size,
                              hipStream_t stream) {
    (void)in_sizes; (void)n_in; (void)out_size; (void)ws_size;
    const float* x   = (const float*)d_in[0];
    const int*   ei  = (const int*)d_in[1];
    const float* W1  = (const float*)d_in[2];
    const float* as1 = (const float*)d_in[3];
    const float* ad1 = (const float*)d_in[4];
    const float* b1  = (const float*)d_in[5];
    const float* g1  = (const float*)d_in[6];
    const float* be1 = (const float*)d_in[7];
    const float* W2  = (const float*)d_in[8];
    const float* as2 = (const float*)d_in[9];
    const float* ad2 = (const float*)d_in[10];
    const float* b2  = (const float*)d_in[11];
    const float* g2  = (const float*)d_in[12];
    const float* be2 = (const float*)d_in[13];
    float* out = (float*)d_out;

    char* ws = (char*)d_ws;
    size_t off = 0;
    auto alloc = [&](size_t bytes) -> void* {
        void* p = ws + off;
        off += (bytes + 255) & ~(size_t)255;
        return p;
    };
    bf16*   aggX    = (bf16*)alloc((size_t)NP * HD * 2);      // 51.25 MB
    bf16*   xb      = (bf16*)alloc((size_t)NP * DF * 2);      // 12.8 MB (padded)
    bf16*   Bt2a    = (bf16*)alloc((size_t)DF * HD * 2);      // 128 KB
    bf16*   Bt2b    = (bf16*)alloc((size_t)DF * HD * 2);
    float*  wsd     = (float*)alloc(2 * 1024 * 4);            // 8 KB
    float*  a_src   = (float*)alloc((size_t)NN * NH * 4);
    float*  a_dst   = (float*)alloc((size_t)NN * NH * 4);
    int*    row_ptr = (int*)alloc((size_t)(NN + 1) * 4);
    int*    bsum    = (int*)alloc(256 * 4);
    int*    colidx  = (int*)alloc((size_t)ET * 4);
    __half* alpha   = (__half*)alloc((size_t)ET * 8);         // 6.8 MB
    float*  agg     = (float*)alloc((size_t)NN * DF * 4);     // 25.6 MB
    float*  stats   = (float*)alloc(256 * 4);
    // counts (padded 64B/dst, 3.2MB) + rank (3.4MB) aliased into agg
    // (agg is first written by gemm_out, long after CSR build completes)
    int*    counts  = (int*)agg;
    int*    rank    = (int*)((char*)agg + ((size_t)NP << 6));
    // high-water ~102 MB (<= R1-proven 107.4 MB)

    const int NB = (NN + 255) / 256;        // 196
    const int EB2 = (ET / 2 + 255) / 256;   // 1661
    dim3 ogrid(NP / 64, 2);                 // 782 x 2

    // ---- prep + CSR build (single atomic pass) ----
    cvt_x_bf16<<<(NN * DF / 4 + 255) / 256, 256, 0, stream>>>(x, xb);
    make_wsd<<<8, 256, 0, stream>>>(W1, as1, ad1, W2, as2, ad2, wsd);
    cvt_bt2<<<(2 * DF * HD + 255) / 256, 256, 0, stream>>>(W1, W2, Bt2a, Bt2b);
    hipMemsetAsync(counts, 0, (size_t)NP << 6, stream);
    count_rank<<<EB2, 256, 0, stream>>>(ei, counts, rank);
    scan1<<<NB, 256, 0, stream>>>(counts, bsum);
    scan2<<<1, 256, 0, stream>>>(bsum, NB);
    scan3<<<NB, 256, 0, stream>>>(counts, bsum, row_ptr);
    fill_scatter<<<EB2, 256, 0, stream>>>(ei, rank, row_ptr, colidx);

    // ---- layer 1 ----
    xscore<<<NN / 4, 256, 0, stream>>>(xb, wsd, a_src, a_dst);
    edge_alpha<<<NN / 4, 256, 0, stream>>>(a_src, a_dst, row_ptr, colidx, alpha);
    aggregate_x<<<NN / 4, 256, 0, stream>>>(xb, alpha, row_ptr, colidx, aggX);
    hipMemsetAsync(stats, 0, 256 * 4, stream);
    gemm_out<<<ogrid, 256, 0, stream>>>(aggX, Bt2a, b1, agg, stats, NN);
    bn_apply_bf16<<<(NN * DF + 255) / 256, 256, 0, stream>>>(agg, stats, g1, be1, xb);

    // ---- layer 2 ----
    xscore<<<NN / 4, 256, 0, stream>>>(xb, wsd + 1024, a_src, a_dst);
    edge_alpha<<<NN / 4, 256, 0, stream>>>(a_src, a_dst, row_ptr, colidx, alpha);
    aggregate_x<<<NN / 4, 256, 0, stream>>>(xb, alpha, row_ptr, colidx, aggX);
    hipMemsetAsync(stats, 0, 256 * 4, stream);
    gemm_out<<<ogrid, 256, 0, stream>>>(aggX, Bt2b, b2, agg, stats, NN);
    bn_apply<<<(NN * DF + 255) / 256, 256, 0, stream>>>(agg, stats, g2, be2, out);
}

// Round 12
// 408.832 us; speedup vs baseline: 1.2127x; 1.0397x over previous
//
#include <hip/hip_runtime.h>
#include <hip/hip_bf16.h>
#include <hip/hip_fp16.h>
#include <math.h>

#define NN 50000
#define NP 50048            // NN padded to 64-row tiles
#define NE 800000
#define ET (NE + NN)
#define DF 128
#define NH 4
#define HD 512
#define BN_EPS 1e-5f

typedef __hip_bfloat16 bf16;
typedef __attribute__((ext_vector_type(8))) short bf16x8;
typedef __attribute__((ext_vector_type(4))) float f32x4;

struct alignas(8) h2x2 { __half2 a, b; };

// ---------- input conversions ----------
__global__ __launch_bounds__(256) void cvt_x_bf16(const float* __restrict__ in, bf16* __restrict__ out) {
    int i = blockIdx.x * 256 + threadIdx.x;            // 4 elements per thread
    if (i >= NN * DF / 4) return;
    float4 v = reinterpret_cast<const float4*>(in)[i];
    union { bf16 b[4]; short4 s; } u;
    u.b[0] = __float2bfloat16(v.x); u.b[1] = __float2bfloat16(v.y);
    u.b[2] = __float2bfloat16(v.z); u.b[3] = __float2bfloat16(v.w);
    reinterpret_cast<short4*>(out)[i] = u.s;
}

// wsd[layer][o][d] = sum_c W[d, h*128+c] * att[h][c],  o=h (src, 0..3) or 4+h (dst)
__global__ __launch_bounds__(256) void make_wsd(const float* __restrict__ W1, const float* __restrict__ as1,
                                                const float* __restrict__ ad1,
                                                const float* __restrict__ W2, const float* __restrict__ as2,
                                                const float* __restrict__ ad2,
                                                float* __restrict__ wsd) {
    int t = blockIdx.x * 256 + threadIdx.x;   // 0..2047
    if (t >= 2048) return;
    int layer = t >> 10;
    int o = (t >> 7) & 7;
    int d = t & 127;
    int h = o & 3;
    const float* W  = layer ? W2 : W1;
    const float* av = layer ? (o < 4 ? as2 : ad2) : (o < 4 ? as1 : ad1);
    const float* wrow = W + d * HD + h * DF;
    const float* arow = av + h * DF;
    float sum = 0.f;
    for (int c = 0; c < DF; ++c) sum += wrow[c] * arow[c];
    wsd[layer * 1024 + o * DF + d] = sum;
}

// Bt2[layer][c][h*128+d] = 0.25 * W[d][h*128+c]   (stacked, transposed, head-mean folded)
__global__ __launch_bounds__(256) void cvt_bt2(const float* __restrict__ W1, const float* __restrict__ W2,
                                               bf16* __restrict__ B1, bf16* __restrict__ B2) {
    int i = blockIdx.x * 256 + threadIdx.x;   // 0..131071
    if (i >= 2 * DF * HD) return;
    int layer = i >> 16;
    int ii = i & 65535;
    int c = ii >> 9, k = ii & 511;
    int h = k >> 7, d = k & 127;
    const float* W = layer ? W2 : W1;
    bf16* B = layer ? B2 : B1;
    B[ii] = __float2bfloat16(0.25f * W[d * HD + h * DF + c]);
}

// ---------- per-node scores from x: a[n,o] = <x[n], wsd[o]> ----------
__global__ __launch_bounds__(256) void xscore(const bf16* __restrict__ X,
                                              const float* __restrict__ wsd,   // [8][128]
                                              float* __restrict__ a_src,
                                              float* __restrict__ a_dst) {
    __shared__ float w[8][DF];
    reinterpret_cast<float4*>(&w[0][0])[threadIdx.x] = reinterpret_cast<const float4*>(wsd)[threadIdx.x];
    __syncthreads();
    const int n = blockIdx.x * 4 + (threadIdx.x >> 6);
    const int l = threadIdx.x & 63;          // lane owns features 2l, 2l+1
    unsigned xv = reinterpret_cast<const unsigned*>(X)[n * 64 + l];
    float x0 = __uint_as_float(xv << 16);
    float x1 = __uint_as_float(xv & 0xffff0000u);
    float v[8];
    #pragma unroll
    for (int o = 0; o < 8; ++o)
        v[o] = x0 * w[o][2 * l] + x1 * w[o][2 * l + 1];
    #pragma unroll
    for (int off = 1; off < 64; off <<= 1) {
        #pragma unroll
        for (int o = 0; o < 8; ++o) v[o] += __shfl_xor(v[o], off);
    }
    if (l == 0) {
        reinterpret_cast<float4*>(a_src)[n] = make_float4(v[0], v[1], v[2], v[3]);
        reinterpret_cast<float4*>(a_dst)[n] = make_float4(v[4], v[5], v[6], v[7]);
    }
}

// ---------- CSR build: single atomic pass (rank trick) ----------
__global__ __launch_bounds__(256) void count_rank(const int* __restrict__ ei, int* __restrict__ counts,
                                                  int* __restrict__ rank) {
    int e = (blockIdx.x * 256 + threadIdx.x) * 2;
    if (e >= ET) return;
    int d0, d1;
    if (e + 1 < NE) {
        int2 dd = *reinterpret_cast<const int2*>(ei + NE + e);
        d0 = dd.x; d1 = dd.y;
    } else {
        d0 = (e < NE) ? ei[NE + e] : (e - NE);
        d1 = (e + 1 < NE) ? ei[NE + e + 1] : (e + 1 - NE);
    }
    rank[e]     = atomicAdd(&counts[d0 << 4], 1);
    rank[e + 1] = atomicAdd(&counts[d1 << 4], 1);
}

__global__ __launch_bounds__(256) void scan1(const int* __restrict__ counts, int* __restrict__ bsum) {
    __shared__ int sd[256];
    int i = blockIdx.x * 256 + threadIdx.x;
    sd[threadIdx.x] = (i < NN) ? counts[i << 4] : 0;
    __syncthreads();
    for (int s = 128; s > 0; s >>= 1) {
        if (threadIdx.x < s) sd[threadIdx.x] += sd[threadIdx.x + s];
        __syncthreads();
    }
    if (threadIdx.x == 0) bsum[blockIdx.x] = sd[0];
}

// parallel exclusive scan over <=256 block sums (Hillis-Steele)
__global__ __launch_bounds__(256) void scan2(int* __restrict__ bsum, int nb) {
    __shared__ int sd[256];
    int i = threadIdx.x;
    int v = (i < nb) ? bsum[i] : 0;
    sd[i] = v;
    __syncthreads();
    for (int s = 1; s < 256; s <<= 1) {
        int t = sd[i];
        int u = (i >= s) ? sd[i - s] : 0;
        __syncthreads();
        sd[i] = t + u;
        __syncthreads();
    }
    if (i < nb) bsum[i] = sd[i] - v;
}

__global__ __launch_bounds__(256) void scan3(const int* __restrict__ counts, const int* __restrict__ bsum,
                                             int* __restrict__ row_ptr) {
    __shared__ int sd[256];
    int i = blockIdx.x * 256 + threadIdx.x;
    int v = (i < NN) ? counts[i << 4] : 0;
    sd[threadIdx.x] = v;
    __syncthreads();
    for (int s = 1; s < 256; s <<= 1) {
        int t = sd[threadIdx.x];
        int u = (threadIdx.x >= s) ? sd[threadIdx.x - s] : 0;
        __syncthreads();
        sd[threadIdx.x] = t + u;
        __syncthreads();
    }
    int excl = sd[threadIdx.x] - v + bsum[blockIdx.x];
    if (i < NN) row_ptr[i] = excl;
    if (i == 0) row_ptr[NN] = ET;
}

// non-atomic scatter: col[row_ptr[d] + rank[e]] = src(e)
__global__ __launch_bounds__(256) void fill_scatter(const int* __restrict__ ei, const int* __restrict__ rank,
                                                    const int* __restrict__ row_ptr, int* __restrict__ col) {
    int e = (blockIdx.x * 256 + threadIdx.x) * 2;
    if (e >= ET) return;
    int s0, d0, s1, d1;
    if (e + 1 < NE) {
        int2 ss = *reinterpret_cast<const int2*>(ei + e);
        int2 dd = *reinterpret_cast<const int2*>(ei + NE + e);
        s0 = ss.x; s1 = ss.y; d0 = dd.x; d1 = dd.y;
    } else {
        if (e < NE) { s0 = ei[e]; d0 = ei[NE + e]; } else { s0 = d0 = e - NE; }
        if (e + 1 < NE) { s1 = ei[e + 1]; d1 = ei[NE + e + 1]; } else { s1 = d1 = e + 1 - NE; }
    }
    int2 rk = *reinterpret_cast<const int2*>(rank + e);
    col[row_ptr[d0] + rk.x] = s0;
    col[row_ptr[d1] + rk.y] = s1;
}

// ---------- per-edge alpha: one WAVE per node, single gather pass ----------
__global__ __launch_bounds__(256) void edge_alpha(const float* __restrict__ a_src,
                                                  const float* __restrict__ a_dst,
                                                  const int* __restrict__ row_ptr,
                                                  const int* __restrict__ col,
                                                  __half* __restrict__ alpha) {
    const int n = blockIdx.x * 4 + (threadIdx.x >> 6);
    const int l = threadIdx.x & 63;
    const int start = row_ptr[n], end = row_ptr[n + 1];
    const float4 ad4 = reinterpret_cast<const float4*>(a_dst)[n];
    const float4* __restrict__ as4 = reinterpret_cast<const float4*>(a_src);
    if (end - start <= 64) {                       // common case: deg <= 64
        const int j = start + l;
        float lv[4] = {-1e30f, -1e30f, -1e30f, -1e30f};
        if (j < end) {
            float4 a = as4[col[j]];
            lv[0] = a.x + ad4.x; lv[1] = a.y + ad4.y; lv[2] = a.z + ad4.z; lv[3] = a.w + ad4.w;
            #pragma unroll
            for (int h = 0; h < 4; ++h) lv[h] = lv[h] > 0.f ? lv[h] : 0.2f * lv[h];
        }
        float m[4], p[4], s[4];
        #pragma unroll
        for (int h = 0; h < 4; ++h) m[h] = lv[h];
        #pragma unroll
        for (int off = 1; off < 64; off <<= 1) {
            #pragma unroll
            for (int h = 0; h < 4; ++h) m[h] = fmaxf(m[h], __shfl_xor(m[h], off));
        }
        #pragma unroll
        for (int h = 0; h < 4; ++h) { p[h] = (j < end) ? __expf(lv[h] - m[h]) : 0.f; s[h] = p[h]; }
        #pragma unroll
        for (int off = 1; off < 64; off <<= 1) {
            #pragma unroll
            for (int h = 0; h < 4; ++h) s[h] += __shfl_xor(s[h], off);
        }
        if (j < end) {
            h2x2 o;
            o.a = __floats2half2_rn(p[0] / s[0], p[1] / s[1]);
            o.b = __floats2half2_rn(p[2] / s[2], p[3] / s[3]);
            reinterpret_cast<h2x2*>(alpha)[j] = o;
        }
    } else {                                       // rare: deg > 64, chunked online
        float m[4] = {-1e30f, -1e30f, -1e30f, -1e30f}, s[4] = {0.f, 0.f, 0.f, 0.f};
        for (int base = start; base < end; base += 64) {
            const int j = base + l;
            float lv[4] = {-1e30f, -1e30f, -1e30f, -1e30f};
            if (j < end) {
                float4 a = as4[col[j]];
                lv[0] = a.x + ad4.x; lv[1] = a.y + ad4.y; lv[2] = a.z + ad4.z; lv[3] = a.w + ad4.w;
                #pragma unroll
                for (int h = 0; h < 4; ++h) lv[h] = lv[h] > 0.f ? lv[h] : 0.2f * lv[h];
            }
            float cm[4], cp[4];
            #pragma unroll
            for (int h = 0; h < 4; ++h) cm[h] = lv[h];
            #pragma unroll
            for (int off = 1; off < 64; off <<= 1) {
                #pragma unroll
                for (int h = 0; h < 4; ++h) cm[h] = fmaxf(cm[h], __shfl_xor(cm[h], off));
            }
            #pragma unroll
            for (int h = 0; h < 4; ++h) {
                float nm = fmaxf(m[h], cm[h]);
                cp[h] = (j < end) ? __expf(lv[h] - nm) : 0.f;
                s[h] *= __expf(m[h] - nm);
                m[h] = nm;
            }
            #pragma unroll
            for (int off = 1; off < 64; off <<= 1) {
                #pragma unroll
                for (int h = 0; h < 4; ++h) cp[h] += __shfl_xor(cp[h], off);
            }
            #pragma unroll
            for (int h = 0; h < 4; ++h) s[h] += cp[h];
        }
        for (int base = start; base < end; base += 64) {
            const int j = base + l;
            if (j < end) {
                float4 a = as4[col[j]];
                float v0 = a.x + ad4.x, v1 = a.y + ad4.y, v2 = a.z + ad4.z, v3 = a.w + ad4.w;
                v0 = v0 > 0.f ? v0 : 0.2f * v0; v1 = v1 > 0.f ? v1 : 0.2f * v1;
                v2 = v2 > 0.f ? v2 : 0.2f * v2; v3 = v3 > 0.f ? v3 : 0.2f * v3;
                h2x2 o;
                o.a = __floats2half2_rn(__expf(v0 - m[0]) / s[0], __expf(v1 - m[1]) / s[1]);
                o.b = __floats2half2_rn(__expf(v2 - m[2]) / s[2], __expf(v3 - m[3]) / s[3]);
                reinterpret_cast<h2x2*>(alpha)[j] = o;
            }
        }
    }
}

// ---------- head-weighted x gather: aggX[n][h*128+d] = sum_e alpha[e,h] x[src,d] ----------
#define EDGE(xu, pu) {                                                               \
    float lo = __uint_as_float((xu) << 16);                                          \
    float hi = __uint_as_float((xu) & 0xffff0000u);                                  \
    float2 f01 = __half22float2(*reinterpret_cast<const __half2*>(&(pu).x));         \
    float2 f23 = __half22float2(*reinterpret_cast<const __half2*>(&(pu).y));         \
    acc[0][0] += f01.x * lo; acc[0][1] += f01.x * hi;                                \
    acc[1][0] += f01.y * lo; acc[1][1] += f01.y * hi;                                \
    acc[2][0] += f23.x * lo; acc[2][1] += f23.x * hi;                                \
    acc[3][0] += f23.y * lo; acc[3][1] += f23.y * hi; }

__global__ __launch_bounds__(256) void aggregate_x(const bf16* __restrict__ X,
                                                   const __half* __restrict__ alpha,
                                                   const int* __restrict__ row_ptr,
                                                   const int* __restrict__ col,
                                                   bf16* __restrict__ aggX) {
    const int n = blockIdx.x * 4 + (threadIdx.x >> 6);
    const int l = threadIdx.x & 63;          // lane owns x features 2l, 2l+1
    const int start = row_ptr[n], end = row_ptr[n + 1];
    const unsigned* __restrict__ X4 = reinterpret_cast<const unsigned*>(X);
    float acc[4][2] = {};
    int j = start;
    for (; j + 4 <= end; j += 4) {
        int c0 = col[j], c1 = col[j + 1], c2 = col[j + 2], c3 = col[j + 3];
        unsigned x0 = X4[c0 * 64 + l];
        unsigned x1 = X4[c1 * 64 + l];
        unsigned x2 = X4[c2 * 64 + l];
        unsigned x3 = X4[c3 * 64 + l];
        uint2 p0 = *reinterpret_cast<const uint2*>(alpha + 4 * j);
        uint2 p1 = *reinterpret_cast<const uint2*>(alpha + 4 * (j + 1));
        uint2 p2 = *reinterpret_cast<const uint2*>(alpha + 4 * (j + 2));
        uint2 p3 = *reinterpret_cast<const uint2*>(alpha + 4 * (j + 3));
        EDGE(x0, p0) EDGE(x1, p1) EDGE(x2, p2) EDGE(x3, p3)
    }
    for (; j < end; ++j) {
        unsigned x0 = X4[col[j] * 64 + l];
        uint2 p0 = *reinterpret_cast<const uint2*>(alpha + 4 * j);
        EDGE(x0, p0)
    }
    unsigned* outp = reinterpret_cast<unsigned*>(aggX) + (size_t)n * 256;
    #pragma unroll
    for (int h = 0; h < 4; ++h) {
        union { bf16 b; unsigned short u; } plo, phi;
        plo.b = __float2bfloat16(acc[h][0]);
        phi.b = __float2bfloat16(acc[h][1]);
        outp[h * 64 + l] = (unsigned)plo.u | ((unsigned)phi.u << 16);
    }
}

// ---------- MFMA GEMM: agg[M,128](bf16) = A[M,512](bf16) @ Bt[128,512]^T + bias ----------
// K-chunks of 64 (128B/row): LDS 2x8KB per matrix = 32KB -> 4 blocks/CU.
// Fused BN-stats epilogue (f32 accumulators -> LDS -> global atomics).
__global__ __launch_bounds__(256) void gemm_out(const bf16* __restrict__ A,
                                                const bf16* __restrict__ Bt,
                                                const float* __restrict__ bias,
                                                bf16* __restrict__ outb,
                                                float* __restrict__ stats, int M) {
    __shared__ __align__(16) char As[2][8192];    // [64 rows][128B k-chunk], XOR-swizzled
    __shared__ __align__(16) char Bs[2][8192];
    __shared__ float ssum[64], ssq[64];
    const int tid = threadIdx.x;
    if (tid < 64) { ssum[tid] = 0.f; ssq[tid] = 0.f; }
    const int m0 = blockIdx.x * 64;
    const int n0 = blockIdx.y * 64;
    const char* Ab = (const char*)A + (size_t)m0 * 1024;     // row stride 512*2 B
    const char* Bb = (const char*)Bt + (size_t)n0 * 1024;
    auto stage = [&](const char* base, char* lds, int kc) {
        #pragma unroll
        for (int i = 0; i < 2; ++i) {
            int d = (tid + i * 256) * 16;    // 0..8191
            int row = d >> 7;                // 128 B per row
            int sw = (d & 127) ^ ((row & 7) << 4);
            __builtin_amdgcn_global_load_lds(
                (const __attribute__((address_space(1))) void*)(base + (size_t)row * 1024 + kc * 128 + sw),
                (__attribute__((address_space(3))) void*)(lds + d), 16, 0, 0);
        }
    };
    stage(Ab, As[0], 0);
    stage(Bb, Bs[0], 0);
    const int lane = tid & 63;
    const int wave = tid >> 6;
    const int wm = (wave & 1) * 32;
    const int wn = (wave >> 1) * 32;
    const int lr = lane & 15;
    const int lkb = (lane >> 4) * 16;
    f32x4 acc[2][2] = {};
    for (int kc = 0; kc < 8; ++kc) {
        __syncthreads();                     // staging for chunk kc complete
        if (kc < 7) {
            stage(Ab, As[(kc + 1) & 1], kc + 1);
            stage(Bb, Bs[(kc + 1) & 1], kc + 1);
        }
        const char* Ac = As[kc & 1];
        const char* Bc = Bs[kc & 1];
        #pragma unroll
        for (int kk = 0; kk < 2; ++kk) {
            int kb = kk * 64 + lkb;
            int ra0 = wm + lr, ra1 = wm + 16 + lr;
            int rb0 = wn + lr, rb1 = wn + 16 + lr;
            bf16x8 a0 = *(const bf16x8*)(Ac + ra0 * 128 + (kb ^ ((ra0 & 7) << 4)));
            bf16x8 a1 = *(const bf16x8*)(Ac + ra1 * 128 + (kb ^ ((ra1 & 7) << 4)));
            bf16x8 b0 = *(const bf16x8*)(Bc + rb0 * 128 + (kb ^ ((rb0 & 7) << 4)));
            bf16x8 b1 = *(const bf16x8*)(Bc + rb1 * 128 + (kb ^ ((rb1 & 7) << 4)));
            acc[0][0] = __builtin_amdgcn_mfma_f32_16x16x32_bf16(a0, b0, acc[0][0], 0, 0, 0);
            acc[0][1] = __builtin_amdgcn_mfma_f32_16x16x32_bf16(a0, b1, acc[0][1], 0, 0, 0);
            acc[1][0] = __builtin_amdgcn_mfma_f32_16x16x32_bf16(a1, b0, acc[1][0], 0, 0, 0);
            acc[1][1] = __builtin_amdgcn_mfma_f32_16x16x32_bf16(a1, b1, acc[1][1], 0, 0, 0);
        }
    }
    const int orow = (lane >> 4) * 4;
    float bcol[2];
    bcol[0] = bias[n0 + wn + lr];
    bcol[1] = bias[n0 + wn + 16 + lr];
    #pragma unroll
    for (int ni = 0; ni < 2; ++ni) {
        float cs = 0.f, cq = 0.f;
        #pragma unroll
        for (int mi = 0; mi < 2; ++mi) {
            #pragma unroll
            for (int r = 0; r < 4; ++r) {
                int gr = m0 + wm + mi * 16 + orow + r;
                if (gr < M) {
                    float v = acc[mi][ni][r] + bcol[ni];
                    outb[(size_t)gr * DF + n0 + wn + ni * 16 + lr] = __float2bfloat16(v);
                    cs += v; cq += v * v;
                }
            }
        }
        atomicAdd(&ssum[wn + ni * 16 + lr], cs);
        atomicAdd(&ssq[wn + ni * 16 + lr], cq);
    }
    __syncthreads();
    if (tid < 64) {
        atomicAdd(&stats[n0 + tid], ssum[tid]);
        atomicAdd(&stats[128 + n0 + tid], ssq[tid]);
    }
}

// ---------- BatchNorm apply (bf16 input, 8 elems/thread) ----------
__device__ __forceinline__ void bn_core(const uint4 v, int c0, const float* stats,
                                        const float* gamma, const float* beta, float* o) {
    float xv[8];
    xv[0] = __uint_as_float(v.x << 16); xv[1] = __uint_as_float(v.x & 0xffff0000u);
    xv[2] = __uint_as_float(v.y << 16); xv[3] = __uint_as_float(v.y & 0xffff0000u);
    xv[4] = __uint_as_float(v.z << 16); xv[5] = __uint_as_float(v.z & 0xffff0000u);
    xv[6] = __uint_as_float(v.w << 16); xv[7] = __uint_as_float(v.w & 0xffff0000u);
    #pragma unroll
    for (int k = 0; k < 8; ++k) {
        int c = c0 + k;
        float mu = stats[c] * (1.f / NN);
        float var = stats[128 + c] * (1.f / NN) - mu * mu;
        o[k] = fmaxf((xv[k] - mu) * rsqrtf(var + BN_EPS) * gamma[c] + beta[c], 0.f);
    }
}

__global__ __launch_bounds__(256) void bn_apply_bf16(const bf16* __restrict__ x, const float* __restrict__ stats,
                                                     const float* __restrict__ gamma, const float* __restrict__ beta,
                                                     bf16* __restrict__ out) {
    int i = blockIdx.x * 256 + threadIdx.x;
    if (i >= NN * DF / 8) return;
    uint4 v = reinterpret_cast<const uint4*>(x)[i];
    float o[8];
    bn_core(v, (i * 8) & 127, stats, gamma, beta, o);
    uint4 w;
    unsigned short* wb = reinterpret_cast<unsigned short*>(&w);
    #pragma unroll
    for (int k = 0; k < 8; ++k) {
        union { bf16 b; unsigned short u; } t;
        t.b = __float2bfloat16(o[k]);
        wb[k] = t.u;
    }
    reinterpret_cast<uint4*>(out)[i] = w;
}

__global__ __launch_bounds__(256) void bn_apply_f32(const bf16* __restrict__ x, const float* __restrict__ stats,
                                                    const float* __restrict__ gamma, const float* __restrict__ beta,
                                                    float* __restrict__ out) {
    int i = blockIdx.x * 256 + threadIdx.x;
    if (i >= NN * DF / 8) return;
    uint4 v = reinterpret_cast<const uint4*>(x)[i];
    float o[8];
    bn_core(v, (i * 8) & 127, stats, gamma, beta, o);
    float4* op = reinterpret_cast<float4*>(out) + (size_t)i * 2;
    op[0] = make_float4(o[0], o[1], o[2], o[3]);
    op[1] = make_float4(o[4], o[5], o[6], o[7]);
}

extern "C" void kernel_launch(void* const* d_in, const int* in_sizes, int n_in,
                              void* d_out, int out_size, void* d_ws, size_t ws_size,
                              hipStream_t stream) {
    (void)in_sizes; (void)n_in; (void)out_size; (void)ws_size;
    const float* x   = (const float*)d_in[0];
    const int*   ei  = (const int*)d_in[1];
    const float* W1  = (const float*)d_in[2];
    const float* as1 = (const float*)d_in[3];
    const float* ad1 = (const float*)d_in[4];
    const float* b1  = (const float*)d_in[5];
    const float* g1  = (const float*)d_in[6];
    const float* be1 = (const float*)d_in[7];
    const float* W2  = (const float*)d_in[8];
    const float* as2 = (const float*)d_in[9];
    const float* ad2 = (const float*)d_in[10];
    const float* b2  = (const float*)d_in[11];
    const float* g2  = (const float*)d_in[12];
    const float* be2 = (const float*)d_in[13];
    float* out = (float*)d_out;

    char* ws = (char*)d_ws;
    size_t off = 0;
    auto alloc = [&](size_t bytes) -> void* {
        void* p = ws + off;
        off += (bytes + 255) & ~(size_t)255;
        return p;
    };
    bf16*   aggX    = (bf16*)alloc((size_t)NP * HD * 2);      // 51.25 MB
    bf16*   xb      = (bf16*)alloc((size_t)NP * DF * 2);      // 12.8 MB (padded)
    bf16*   Bt2a    = (bf16*)alloc((size_t)DF * HD * 2);      // 128 KB
    bf16*   Bt2b    = (bf16*)alloc((size_t)DF * HD * 2);
    float*  wsd     = (float*)alloc(2 * 1024 * 4);            // 8 KB
    float*  a_src   = (float*)alloc((size_t)NN * NH * 4);
    float*  a_dst   = (float*)alloc((size_t)NN * NH * 4);
    int*    row_ptr = (int*)alloc((size_t)(NN + 1) * 4);
    int*    bsum    = (int*)alloc(256 * 4);
    int*    colidx  = (int*)alloc((size_t)ET * 4);
    __half* alpha   = (__half*)alloc((size_t)ET * 8);         // 6.8 MB
    bf16*   agg     = (bf16*)alloc((size_t)NN * DF * 2);      // 12.8 MB (bf16 now)
    float*  stats   = (float*)alloc(256 * 4);
    // counts (padded 64B/dst, 3.2MB) + rank (3.4MB) aliased into agg (12.8MB;
    // agg is first written by gemm_out, long after CSR build completes)
    int*    counts  = (int*)agg;
    int*    rank    = (int*)((char*)agg + ((size_t)NP << 6));
    // high-water ~89 MB (<= R1-proven 107.4 MB)

    const int NB = (NN + 255) / 256;        // 196
    const int EB2 = (ET / 2 + 255) / 256;   // 1661
    dim3 ogrid(NP / 64, 2);                 // 782 x 2
    const int BNB = (NN * DF / 8 + 255) / 256;  // 3125

    // ---- prep + CSR build (single atomic pass) ----
    cvt_x_bf16<<<(NN * DF / 4 + 255) / 256, 256, 0, stream>>>(x, xb);
    make_wsd<<<8, 256, 0, stream>>>(W1, as1, ad1, W2, as2, ad2, wsd);
    cvt_bt2<<<(2 * DF * HD + 255) / 256, 256, 0, stream>>>(W1, W2, Bt2a, Bt2b);
    hipMemsetAsync(counts, 0, (size_t)NP << 6, stream);
    count_rank<<<EB2, 256, 0, stream>>>(ei, counts, rank);
    scan1<<<NB, 256, 0, stream>>>(counts, bsum);
    scan2<<<1, 256, 0, stream>>>(bsum, NB);
    scan3<<<NB, 256, 0, stream>>>(counts, bsum, row_ptr);
    fill_scatter<<<EB2, 256, 0, stream>>>(ei, rank, row_ptr, colidx);

    // ---- layer 1 ----
    xscore<<<NN / 4, 256, 0, stream>>>(xb, wsd, a_src, a_dst);
    edge_alpha<<<NN / 4, 256, 0, stream>>>(a_src, a_dst, row_ptr, colidx, alpha);
    aggregate_x<<<NN / 4, 256, 0, stream>>>(xb, alpha, row_ptr, colidx, aggX);
    hipMemsetAsync(stats, 0, 256 * 4, stream);
    gemm_out<<<ogrid, 256, 0, stream>>>(aggX, Bt2a, b1, agg, stats, NN);
    bn_apply_bf16<<<BNB, 256, 0, stream>>>(agg, stats, g1, be1, xb);

    // ---- layer 2 ----
    xscore<<<NN / 4, 256, 0, stream>>>(xb, wsd + 1024, a_src, a_dst);
    edge_alpha<<<NN / 4, 256, 0, stream>>>(a_src, a_dst, row_ptr, colidx, alpha);
    aggregate_x<<<NN / 4, 256, 0, stream>>>(xb, alpha, row_ptr, colidx, aggX);
    hipMemsetAsync(stats, 0, 256 * 4, stream);
    gemm_out<<<ogrid, 256, 0, stream>>>(aggX, Bt2b, b2, agg, stats, NN);
    bn_apply_f32<<<BNB, 256, 0, stream>>>(agg, stats, g2, be2, out);
}

// Round 13
// 390.356 us; speedup vs baseline: 1.2701x; 1.0473x over previous
//
#include <hip/hip_runtime.h>
#include <hip/hip_bf16.h>
#include <hip/hip_fp16.h>
#include <math.h>

#define NN 50000
#define NP 50048            // NN padded to 64-row tiles
#define NE 800000
#define ET (NE + NN)
#define DF 128
#define NH 4
#define HD 512
#define BN_EPS 1e-5f

typedef __hip_bfloat16 bf16;
typedef __attribute__((ext_vector_type(8))) short bf16x8;
typedef __attribute__((ext_vector_type(4))) float f32x4;

struct alignas(8) h2x2 { __half2 a, b; };

// ---------- input conversions ----------
__global__ __launch_bounds__(256) void cvt_x_bf16(const float* __restrict__ in, bf16* __restrict__ out) {
    int i = blockIdx.x * 256 + threadIdx.x;            // 4 elements per thread
    if (i >= NN * DF / 4) return;
    float4 v = reinterpret_cast<const float4*>(in)[i];
    union { bf16 b[4]; short4 s; } u;
    u.b[0] = __float2bfloat16(v.x); u.b[1] = __float2bfloat16(v.y);
    u.b[2] = __float2bfloat16(v.z); u.b[3] = __float2bfloat16(v.w);
    reinterpret_cast<short4*>(out)[i] = u.s;
}

// wsd[layer][o][d] = sum_c W[d, h*128+c] * att[h][c],  o=h (src, 0..3) or 4+h (dst)
__global__ __launch_bounds__(256) void make_wsd(const float* __restrict__ W1, const float* __restrict__ as1,
                                                const float* __restrict__ ad1,
                                                const float* __restrict__ W2, const float* __restrict__ as2,
                                                const float* __restrict__ ad2,
                                                float* __restrict__ wsd) {
    int t = blockIdx.x * 256 + threadIdx.x;   // 0..2047
    if (t >= 2048) return;
    int layer = t >> 10;
    int o = (t >> 7) & 7;
    int d = t & 127;
    int h = o & 3;
    const float* W  = layer ? W2 : W1;
    const float* av = layer ? (o < 4 ? as2 : ad2) : (o < 4 ? as1 : ad1);
    const float* wrow = W + d * HD + h * DF;
    const float* arow = av + h * DF;
    float sum = 0.f;
    for (int c = 0; c < DF; ++c) sum += wrow[c] * arow[c];
    wsd[layer * 1024 + o * DF + d] = sum;
}

// Bt2[layer][c][h*128+d] = 0.25 * W[d][h*128+c]   (stacked, transposed, head-mean folded)
__global__ __launch_bounds__(256) void cvt_bt2(const float* __restrict__ W1, const float* __restrict__ W2,
                                               bf16* __restrict__ B1, bf16* __restrict__ B2) {
    int i = blockIdx.x * 256 + threadIdx.x;   // 0..131071
    if (i >= 2 * DF * HD) return;
    int layer = i >> 16;
    int ii = i & 65535;
    int c = ii >> 9, k = ii & 511;
    int h = k >> 7, d = k & 127;
    const float* W = layer ? W2 : W1;
    bf16* B = layer ? B2 : B1;
    B[ii] = __float2bfloat16(0.25f * W[d * HD + h * DF + c]);
}

// ---------- per-node scores from x: a[n,o] = <x[n], wsd[o]> ----------
__global__ __launch_bounds__(256) void xscore(const bf16* __restrict__ X,
                                              const float* __restrict__ wsd,   // [8][128]
                                              float* __restrict__ a_src,
                                              float* __restrict__ a_dst) {
    __shared__ float w[8][DF];
    reinterpret_cast<float4*>(&w[0][0])[threadIdx.x] = reinterpret_cast<const float4*>(wsd)[threadIdx.x];
    __syncthreads();
    const int n = blockIdx.x * 4 + (threadIdx.x >> 6);
    const int l = threadIdx.x & 63;          // lane owns features 2l, 2l+1
    unsigned xv = reinterpret_cast<const unsigned*>(X)[n * 64 + l];
    float x0 = __uint_as_float(xv << 16);
    float x1 = __uint_as_float(xv & 0xffff0000u);
    float v[8];
    #pragma unroll
    for (int o = 0; o < 8; ++o)
        v[o] = x0 * w[o][2 * l] + x1 * w[o][2 * l + 1];
    #pragma unroll
    for (int off = 1; off < 64; off <<= 1) {
        #pragma unroll
        for (int o = 0; o < 8; ++o) v[o] += __shfl_xor(v[o], off);
    }
    if (l == 0) {
        reinterpret_cast<float4*>(a_src)[n] = make_float4(v[0], v[1], v[2], v[3]);
        reinterpret_cast<float4*>(a_dst)[n] = make_float4(v[4], v[5], v[6], v[7]);
    }
}

// ---------- CSR build: single atomic pass (rank trick) ----------
__global__ __launch_bounds__(256) void count_rank(const int* __restrict__ ei, int* __restrict__ counts,
                                                  int* __restrict__ rank) {
    int e = (blockIdx.x * 256 + threadIdx.x) * 2;
    if (e >= ET) return;
    int d0, d1;
    if (e + 1 < NE) {
        int2 dd = *reinterpret_cast<const int2*>(ei + NE + e);
        d0 = dd.x; d1 = dd.y;
    } else {
        d0 = (e < NE) ? ei[NE + e] : (e - NE);
        d1 = (e + 1 < NE) ? ei[NE + e + 1] : (e + 1 - NE);
    }
    rank[e]     = atomicAdd(&counts[d0 << 4], 1);
    rank[e + 1] = atomicAdd(&counts[d1 << 4], 1);
}

__global__ __launch_bounds__(256) void scan1(const int* __restrict__ counts, int* __restrict__ bsum) {
    __shared__ int sd[256];
    int i = blockIdx.x * 256 + threadIdx.x;
    sd[threadIdx.x] = (i < NN) ? counts[i << 4] : 0;
    __syncthreads();
    for (int s = 128; s > 0; s >>= 1) {
        if (threadIdx.x < s) sd[threadIdx.x] += sd[threadIdx.x + s];
        __syncthreads();
    }
    if (threadIdx.x == 0) bsum[blockIdx.x] = sd[0];
}

// parallel exclusive scan over <=256 block sums (Hillis-Steele)
__global__ __launch_bounds__(256) void scan2(int* __restrict__ bsum, int nb) {
    __shared__ int sd[256];
    int i = threadIdx.x;
    int v = (i < nb) ? bsum[i] : 0;
    sd[i] = v;
    __syncthreads();
    for (int s = 1; s < 256; s <<= 1) {
        int t = sd[i];
        int u = (i >= s) ? sd[i - s] : 0;
        __syncthreads();
        sd[i] = t + u;
        __syncthreads();
    }
    if (i < nb) bsum[i] = sd[i] - v;
}

__global__ __launch_bounds__(256) void scan3(const int* __restrict__ counts, const int* __restrict__ bsum,
                                             int* __restrict__ row_ptr) {
    __shared__ int sd[256];
    int i = blockIdx.x * 256 + threadIdx.x;
    int v = (i < NN) ? counts[i << 4] : 0;
    sd[threadIdx.x] = v;
    __syncthreads();
    for (int s = 1; s < 256; s <<= 1) {
        int t = sd[threadIdx.x];
        int u = (threadIdx.x >= s) ? sd[threadIdx.x - s] : 0;
        __syncthreads();
        sd[threadIdx.x] = t + u;
        __syncthreads();
    }
    int excl = sd[threadIdx.x] - v + bsum[blockIdx.x];
    if (i < NN) row_ptr[i] = excl;
    if (i == 0) row_ptr[NN] = ET;
}

// non-atomic scatter: col[row_ptr[d] + rank[e]] = src(e)
__global__ __launch_bounds__(256) void fill_scatter(const int* __restrict__ ei, const int* __restrict__ rank,
                                                    const int* __restrict__ row_ptr, int* __restrict__ col) {
    int e = (blockIdx.x * 256 + threadIdx.x) * 2;
    if (e >= ET) return;
    int s0, d0, s1, d1;
    if (e + 1 < NE) {
        int2 ss = *reinterpret_cast<const int2*>(ei + e);
        int2 dd = *reinterpret_cast<const int2*>(ei + NE + e);
        s0 = ss.x; s1 = ss.y; d0 = dd.x; d1 = dd.y;
    } else {
        if (e < NE) { s0 = ei[e]; d0 = ei[NE + e]; } else { s0 = d0 = e - NE; }
        if (e + 1 < NE) { s1 = ei[e + 1]; d1 = ei[NE + e + 1]; } else { s1 = d1 = e + 1 - NE; }
    }
    int2 rk = *reinterpret_cast<const int2*>(rank + e);
    col[row_ptr[d0] + rk.x] = s0;
    col[row_ptr[d1] + rk.y] = s1;
}

// ---------- per-edge alpha: one WAVE per node, single gather pass ----------
__global__ __launch_bounds__(256) void edge_alpha(const float* __restrict__ a_src,
                                                  const float* __restrict__ a_dst,
                                                  const int* __restrict__ row_ptr,
                                                  const int* __restrict__ col,
                                                  __half* __restrict__ alpha) {
    const int n = blockIdx.x * 4 + (threadIdx.x >> 6);
    const int l = threadIdx.x & 63;
    const int start = row_ptr[n], end = row_ptr[n + 1];
    const float4 ad4 = reinterpret_cast<const float4*>(a_dst)[n];
    const float4* __restrict__ as4 = reinterpret_cast<const float4*>(a_src);
    if (end - start <= 64) {                       // common case: deg <= 64
        const int j = start + l;
        float lv[4] = {-1e30f, -1e30f, -1e30f, -1e30f};
        if (j < end) {
            float4 a = as4[col[j]];
            lv[0] = a.x + ad4.x; lv[1] = a.y + ad4.y; lv[2] = a.z + ad4.z; lv[3] = a.w + ad4.w;
            #pragma unroll
            for (int h = 0; h < 4; ++h) lv[h] = lv[h] > 0.f ? lv[h] : 0.2f * lv[h];
        }
        float m[4], p[4], s[4];
        #pragma unroll
        for (int h = 0; h < 4; ++h) m[h] = lv[h];
        #pragma unroll
        for (int off = 1; off < 64; off <<= 1) {
            #pragma unroll
            for (int h = 0; h < 4; ++h) m[h] = fmaxf(m[h], __shfl_xor(m[h], off));
        }
        #pragma unroll
        for (int h = 0; h < 4; ++h) { p[h] = (j < end) ? __expf(lv[h] - m[h]) : 0.f; s[h] = p[h]; }
        #pragma unroll
        for (int off = 1; off < 64; off <<= 1) {
            #pragma unroll
            for (int h = 0; h < 4; ++h) s[h] += __shfl_xor(s[h], off);
        }
        if (j < end) {
            h2x2 o;
            o.a = __floats2half2_rn(p[0] / s[0], p[1] / s[1]);
            o.b = __floats2half2_rn(p[2] / s[2], p[3] / s[3]);
            reinterpret_cast<h2x2*>(alpha)[j] = o;
        }
    } else {                                       // rare: deg > 64, chunked online
        float m[4] = {-1e30f, -1e30f, -1e30f, -1e30f}, s[4] = {0.f, 0.f, 0.f, 0.f};
        for (int base = start; base < end; base += 64) {
            const int j = base + l;
            float lv[4] = {-1e30f, -1e30f, -1e30f, -1e30f};
            if (j < end) {
                float4 a = as4[col[j]];
                lv[0] = a.x + ad4.x; lv[1] = a.y + ad4.y; lv[2] = a.z + ad4.z; lv[3] = a.w + ad4.w;
                #pragma unroll
                for (int h = 0; h < 4; ++h) lv[h] = lv[h] > 0.f ? lv[h] : 0.2f * lv[h];
            }
            float cm[4], cp[4];
            #pragma unroll
            for (int h = 0; h < 4; ++h) cm[h] = lv[h];
            #pragma unroll
            for (int off = 1; off < 64; off <<= 1) {
                #pragma unroll
                for (int h = 0; h < 4; ++h) cm[h] = fmaxf(cm[h], __shfl_xor(cm[h], off));
            }
            #pragma unroll
            for (int h = 0; h < 4; ++h) {
                float nm = fmaxf(m[h], cm[h]);
                cp[h] = (j < end) ? __expf(lv[h] - nm) : 0.f;
                s[h] *= __expf(m[h] - nm);
                m[h] = nm;
            }
            #pragma unroll
            for (int off = 1; off < 64; off <<= 1) {
                #pragma unroll
                for (int h = 0; h < 4; ++h) cp[h] += __shfl_xor(cp[h], off);
            }
            #pragma unroll
            for (int h = 0; h < 4; ++h) s[h] += cp[h];
        }
        for (int base = start; base < end; base += 64) {
            const int j = base + l;
            if (j < end) {
                float4 a = as4[col[j]];
                float v0 = a.x + ad4.x, v1 = a.y + ad4.y, v2 = a.z + ad4.z, v3 = a.w + ad4.w;
                v0 = v0 > 0.f ? v0 : 0.2f * v0; v1 = v1 > 0.f ? v1 : 0.2f * v1;
                v2 = v2 > 0.f ? v2 : 0.2f * v2; v3 = v3 > 0.f ? v3 : 0.2f * v3;
                h2x2 o;
                o.a = __floats2half2_rn(__expf(v0 - m[0]) / s[0], __expf(v1 - m[1]) / s[1]);
                o.b = __floats2half2_rn(__expf(v2 - m[2]) / s[2], __expf(v3 - m[3]) / s[3]);
                reinterpret_cast<h2x2*>(alpha)[j] = o;
            }
        }
    }
}

// ---------- head-weighted x gather: aggX[n][h*128+d] = sum_e alpha[e,h] x[src,d] ----------
#define EDGE(xu, pu) {                                                               \
    float lo = __uint_as_float((xu) << 16);                                          \
    float hi = __uint_as_float((xu) & 0xffff0000u);                                  \
    float2 f01 = __half22float2(*reinterpret_cast<const __half2*>(&(pu).x));         \
    float2 f23 = __half22float2(*reinterpret_cast<const __half2*>(&(pu).y));         \
    acc[0][0] += f01.x * lo; acc[0][1] += f01.x * hi;                                \
    acc[1][0] += f01.y * lo; acc[1][1] += f01.y * hi;                                \
    acc[2][0] += f23.x * lo; acc[2][1] += f23.x * hi;                                \
    acc[3][0] += f23.y * lo; acc[3][1] += f23.y * hi; }

__global__ __launch_bounds__(256) void aggregate_x(const bf16* __restrict__ X,
                                                   const __half* __restrict__ alpha,
                                                   const int* __restrict__ row_ptr,
                                                   const int* __restrict__ col,
                                                   bf16* __restrict__ aggX) {
    const int n = blockIdx.x * 4 + (threadIdx.x >> 6);
    const int l = threadIdx.x & 63;          // lane owns x features 2l, 2l+1
    const int start = row_ptr[n], end = row_ptr[n + 1];
    const unsigned* __restrict__ X4 = reinterpret_cast<const unsigned*>(X);
    float acc[4][2] = {};
    int j = start;
    for (; j + 4 <= end; j += 4) {
        int c0 = col[j], c1 = col[j + 1], c2 = col[j + 2], c3 = col[j + 3];
        unsigned x0 = X4[c0 * 64 + l];
        unsigned x1 = X4[c1 * 64 + l];
        unsigned x2 = X4[c2 * 64 + l];
        unsigned x3 = X4[c3 * 64 + l];
        uint2 p0 = *reinterpret_cast<const uint2*>(alpha + 4 * j);
        uint2 p1 = *reinterpret_cast<const uint2*>(alpha + 4 * (j + 1));
        uint2 p2 = *reinterpret_cast<const uint2*>(alpha + 4 * (j + 2));
        uint2 p3 = *reinterpret_cast<const uint2*>(alpha + 4 * (j + 3));
        EDGE(x0, p0) EDGE(x1, p1) EDGE(x2, p2) EDGE(x3, p3)
    }
    for (; j < end; ++j) {
        unsigned x0 = X4[col[j] * 64 + l];
        uint2 p0 = *reinterpret_cast<const uint2*>(alpha + 4 * j);
        EDGE(x0, p0)
    }
    unsigned* outp = reinterpret_cast<unsigned*>(aggX) + (size_t)n * 256;
    #pragma unroll
    for (int h = 0; h < 4; ++h) {
        union { bf16 b; unsigned short u; } plo, phi;
        plo.b = __float2bfloat16(acc[h][0]);
        phi.b = __float2bfloat16(acc[h][1]);
        outp[h * 64 + l] = (unsigned)plo.u | ((unsigned)phi.u << 16);
    }
}

// ---------- MFMA GEMM: agg[M,128](bf16) = A[M,512](bf16) @ Bt[128,512]^T + bias ----------
// B LDS-resident in two 64KB K-phases; A streamed global->VGPR (no barriers in main loop).
// One block = full 128 output cols x 64-row panel; A fetched exactly once.
__global__ __launch_bounds__(256) void gemm_out(const bf16* __restrict__ A,
                                                const bf16* __restrict__ Bt,
                                                const float* __restrict__ bias,
                                                bf16* __restrict__ outb,
                                                float* __restrict__ stats, int M) {
    __shared__ __align__(16) char Bs[65536];      // [128 cols][512B K-phase], XOR-swizzled
    __shared__ float ssum[128], ssq[128];
    const int tid = threadIdx.x;
    if (tid < 128) { ssum[tid] = 0.f; ssq[tid] = 0.f; }
    const int m0 = blockIdx.x * 64;
    const char* Ab = (const char*)A + (size_t)m0 * 1024;     // row stride 512*2 B
    const char* Bb = (const char*)Bt;
    auto stageB = [&](int ph) {
        #pragma unroll
        for (int i = 0; i < 16; ++i) {
            int d = (tid + i * 256) * 16;        // 0..65535
            int c = d >> 9;                      // col 0..127
            int kb = d & 511;
            int src = c * 1024 + ph * 512 + (kb ^ ((c & 7) << 4));
            __builtin_amdgcn_global_load_lds(
                (const __attribute__((address_space(1))) void*)(Bb + src),
                (__attribute__((address_space(3))) void*)(Bs + d), 16, 0, 0);
        }
    };
    const int lane = tid & 63;
    const int wave = tid >> 6;
    const int wm = (wave & 1) * 32;               // m-offset
    const int wnb = (wave >> 1) * 64;             // col base (0 or 64)
    const int lr = lane & 15;
    const int lkb = (lane >> 4) * 16;
    f32x4 acc[2][4] = {};
    const char* arow0 = Ab + (size_t)(wm + lr) * 1024 + lkb;
    const char* arow1 = Ab + (size_t)(wm + 16 + lr) * 1024 + lkb;
    stageB(0);
    #pragma unroll
    for (int ph = 0; ph < 2; ++ph) {
        __syncthreads();                          // stage(ph) complete
        #pragma unroll 4
        for (int kk = 0; kk < 8; ++kk) {
            int kg = ph * 512 + kk * 64;
            bf16x8 a0 = *(const bf16x8*)(arow0 + kg);
            bf16x8 a1 = *(const bf16x8*)(arow1 + kg);
            int kb = kk * 64 + lkb;
            #pragma unroll
            for (int nf = 0; nf < 4; ++nf) {
                int c = wnb + nf * 16 + lr;
                bf16x8 b = *(const bf16x8*)(Bs + c * 512 + (kb ^ ((c & 7) << 4)));
                acc[0][nf] = __builtin_amdgcn_mfma_f32_16x16x32_bf16(a0, b, acc[0][nf], 0, 0, 0);
                acc[1][nf] = __builtin_amdgcn_mfma_f32_16x16x32_bf16(a1, b, acc[1][nf], 0, 0, 0);
            }
        }
        if (ph == 0) {
            __syncthreads();                      // all reads of phase-0 B done
            stageB(1);
        }
    }
    const int orow = (lane >> 4) * 4;
    float bcol[4];
    #pragma unroll
    for (int nf = 0; nf < 4; ++nf) bcol[nf] = bias[wnb + nf * 16 + lr];
    #pragma unroll
    for (int nf = 0; nf < 4; ++nf) {
        float cs = 0.f, cq = 0.f;
        int c = wnb + nf * 16 + lr;
        #pragma unroll
        for (int mi = 0; mi < 2; ++mi) {
            #pragma unroll
            for (int r = 0; r < 4; ++r) {
                int gr = m0 + wm + mi * 16 + orow + r;
                if (gr < M) {
                    float v = acc[mi][nf][r] + bcol[nf];
                    outb[(size_t)gr * DF + c] = __float2bfloat16(v);
                    cs += v; cq += v * v;
                }
            }
        }
        atomicAdd(&ssum[c], cs);
        atomicAdd(&ssq[c], cq);
    }
    __syncthreads();
    if (tid < 128) {
        atomicAdd(&stats[tid], ssum[tid]);
        atomicAdd(&stats[128 + tid], ssq[tid]);
    }
}

// ---------- BatchNorm apply (bf16 input, 8 elems/thread) ----------
__device__ __forceinline__ void bn_core(const uint4 v, int c0, const float* stats,
                                        const float* gamma, const float* beta, float* o) {
    float xv[8];
    xv[0] = __uint_as_float(v.x << 16); xv[1] = __uint_as_float(v.x & 0xffff0000u);
    xv[2] = __uint_as_float(v.y << 16); xv[3] = __uint_as_float(v.y & 0xffff0000u);
    xv[4] = __uint_as_float(v.z << 16); xv[5] = __uint_as_float(v.z & 0xffff0000u);
    xv[6] = __uint_as_float(v.w << 16); xv[7] = __uint_as_float(v.w & 0xffff0000u);
    #pragma unroll
    for (int k = 0; k < 8; ++k) {
        int c = c0 + k;
        float mu = stats[c] * (1.f / NN);
        float var = stats[128 + c] * (1.f / NN) - mu * mu;
        o[k] = fmaxf((xv[k] - mu) * rsqrtf(var + BN_EPS) * gamma[c] + beta[c], 0.f);
    }
}

__global__ __launch_bounds__(256) void bn_apply_bf16(const bf16* __restrict__ x, const float* __restrict__ stats,
                                                     const float* __restrict__ gamma, const float* __restrict__ beta,
                                                     bf16* __restrict__ out) {
    int i = blockIdx.x * 256 + threadIdx.x;
    if (i >= NN * DF / 8) return;
    uint4 v = reinterpret_cast<const uint4*>(x)[i];
    float o[8];
    bn_core(v, (i * 8) & 127, stats, gamma, beta, o);
    uint4 w;
    unsigned short* wb = reinterpret_cast<unsigned short*>(&w);
    #pragma unroll
    for (int k = 0; k < 8; ++k) {
        union { bf16 b; unsigned short u; } t;
        t.b = __float2bfloat16(o[k]);
        wb[k] = t.u;
    }
    reinterpret_cast<uint4*>(out)[i] = w;
}

__global__ __launch_bounds__(256) void bn_apply_f32(const bf16* __restrict__ x, const float* __restrict__ stats,
                                                    const float* __restrict__ gamma, const float* __restrict__ beta,
                                                    float* __restrict__ out) {
    int i = blockIdx.x * 256 + threadIdx.x;
    if (i >= NN * DF / 8) return;
    uint4 v = reinterpret_cast<const uint4*>(x)[i];
    float o[8];
    bn_core(v, (i * 8) & 127, stats, gamma, beta, o);
    float4* op = reinterpret_cast<float4*>(out) + (size_t)i * 2;
    op[0] = make_float4(o[0], o[1], o[2], o[3]);
    op[1] = make_float4(o[4], o[5], o[6], o[7]);
}

extern "C" void kernel_launch(void* const* d_in, const int* in_sizes, int n_in,
                              void* d_out, int out_size, void* d_ws, size_t ws_size,
                              hipStream_t stream) {
    (void)in_sizes; (void)n_in; (void)out_size; (void)ws_size;
    const float* x   = (const float*)d_in[0];
    const int*   ei  = (const int*)d_in[1];
    const float* W1  = (const float*)d_in[2];
    const float* as1 = (const float*)d_in[3];
    const float* ad1 = (const float*)d_in[4];
    const float* b1  = (const float*)d_in[5];
    const float* g1  = (const float*)d_in[6];
    const float* be1 = (const float*)d_in[7];
    const float* W2  = (const float*)d_in[8];
    const float* as2 = (const float*)d_in[9];
    const float* ad2 = (const float*)d_in[10];
    const float* b2  = (const float*)d_in[11];
    const float* g2  = (const float*)d_in[12];
    const float* be2 = (const float*)d_in[13];
    float* out = (float*)d_out;

    char* ws = (char*)d_ws;
    size_t off = 0;
    auto alloc = [&](size_t bytes) -> void* {
        void* p = ws + off;
        off += (bytes + 255) & ~(size_t)255;
        return p;
    };
    bf16*   aggX    = (bf16*)alloc((size_t)NP * HD * 2);      // 51.25 MB
    bf16*   xb      = (bf16*)alloc((size_t)NP * DF * 2);      // 12.8 MB (padded)
    bf16*   Bt2a    = (bf16*)alloc((size_t)DF * HD * 2);      // 128 KB
    bf16*   Bt2b    = (bf16*)alloc((size_t)DF * HD * 2);
    float*  wsd     = (float*)alloc(2 * 1024 * 4);            // 8 KB
    float*  a_src   = (float*)alloc((size_t)NN * NH * 4);
    float*  a_dst   = (float*)alloc((size_t)NN * NH * 4);
    int*    row_ptr = (int*)alloc((size_t)(NN + 1) * 4);
    int*    bsum    = (int*)alloc(256 * 4);
    int*    colidx  = (int*)alloc((size_t)ET * 4);
    __half* alpha   = (__half*)alloc((size_t)ET * 8);         // 6.8 MB
    bf16*   agg     = (bf16*)alloc((size_t)NN * DF * 2);      // 12.8 MB (bf16)
    float*  stats   = (float*)alloc(256 * 4);
    // counts (padded 64B/dst, 3.2MB) + rank (3.4MB) aliased into agg+aggX region:
    // agg first written by gemm_out, long after CSR build completes
    int*    counts  = (int*)agg;
    int*    rank    = (int*)((char*)agg + ((size_t)NP << 6));
    // high-water ~89 MB (<= R1-proven 107.4 MB)

    const int NB = (NN + 255) / 256;        // 196
    const int EB2 = (ET / 2 + 255) / 256;   // 1661
    const int BNB = (NN * DF / 8 + 255) / 256;  // 3125

    // ---- prep + CSR build (single atomic pass) ----
    cvt_x_bf16<<<(NN * DF / 4 + 255) / 256, 256, 0, stream>>>(x, xb);
    make_wsd<<<8, 256, 0, stream>>>(W1, as1, ad1, W2, as2, ad2, wsd);
    cvt_bt2<<<(2 * DF * HD + 255) / 256, 256, 0, stream>>>(W1, W2, Bt2a, Bt2b);
    hipMemsetAsync(counts, 0, (size_t)NP << 6, stream);
    count_rank<<<EB2, 256, 0, stream>>>(ei, counts, rank);
    scan1<<<NB, 256, 0, stream>>>(counts, bsum);
    scan2<<<1, 256, 0, stream>>>(bsum, NB);
    scan3<<<NB, 256, 0, stream>>>(counts, bsum, row_ptr);
    fill_scatter<<<EB2, 256, 0, stream>>>(ei, rank, row_ptr, colidx);

    // ---- layer 1 ----
    xscore<<<NN / 4, 256, 0, stream>>>(xb, wsd, a_src, a_dst);
    edge_alpha<<<NN / 4, 256, 0, stream>>>(a_src, a_dst, row_ptr, colidx, alpha);
    aggregate_x<<<NN / 4, 256, 0, stream>>>(xb, alpha, row_ptr, colidx, aggX);
    hipMemsetAsync(stats, 0, 256 * 4, stream);
    gemm_out<<<NP / 64, 256, 0, stream>>>(aggX, Bt2a, b1, agg, stats, NN);
    bn_apply_bf16<<<BNB, 256, 0, stream>>>(agg, stats, g1, be1, xb);

    // ---- layer 2 ----
    xscore<<<NN / 4, 256, 0, stream>>>(xb, wsd + 1024, a_src, a_dst);
    edge_alpha<<<NN / 4, 256, 0, stream>>>(a_src, a_dst, row_ptr, colidx, alpha);
    aggregate_x<<<NN / 4, 256, 0, stream>>>(xb, alpha, row_ptr, colidx, aggX);
    hipMemsetAsync(stats, 0, 256 * 4, stream);
    gemm_out<<<NP / 64, 256, 0, stream>>>(aggX, Bt2b, b2, agg, stats, NN);
    bn_apply_f32<<<BNB, 256, 0, stream>>>(agg, stats, g2, be2, out);
}